// Round 1
// baseline (715.992 us; speedup 1.0000x reference)
//
#include <hip/hip_runtime.h>
#include <math.h>

static constexpr int B_ = 8;
static constexpr int L_ = 4096;
static constexpr int D_ = 512;
static constexpr int U_ = 45;
static constexpr float SCALE_ = 0.04419417382415922f; // 1/sqrt(512)

// ---- workspace layout (offsets in floats) ----
static constexpr size_t OFF_WVMEAN = 0;                      // 512
static constexpr size_t OFF_BV     = 512;                    // 64
static constexpr size_t OFF_WQT    = 576;                    // 512*512
static constexpr size_t OFF_WKT    = OFF_WQT + 262144;       // 512*512
static constexpr size_t OFF_KBAR   = OFF_WKT + 262144;       // 8*45*512
static constexpr size_t OFF_KW     = OFF_KBAR + 184320;      // 8*45*512
static constexpr size_t OFF_CVEC   = OFF_KW + 184320;        // 384
static constexpr size_t OFF_MEAS   = OFF_CVEC + 384;         // 8*4096
static constexpr size_t OFF_TOPI   = OFF_MEAS + 32768;       // 384 (ints)
static constexpr size_t OFF_QBAR   = OFF_TOPI + 384;         // 8*45*512
static constexpr size_t OFF_QW     = OFF_QBAR + 184320;      // 8*45*512
static constexpr size_t OFF_DVEC   = OFF_QW + 184320;        // 384
static constexpr size_t OFF_SC     = OFF_DVEC + 384;         // 8*45*4096
static constexpr size_t OFF_PART   = OFF_SC + 1474560;       // 8*(8*45*512)
static constexpr size_t OFF_ATTNV  = OFF_PART + 1474560;     // 8*45*512
static constexpr size_t OFF_S1     = OFF_ATTNV + 184320;     // 8*45*512

__device__ __forceinline__ float wave_sum(float v) {
  #pragma unroll
  for (int m = 32; m; m >>= 1) v += __shfl_xor(v, m, 64);
  return v;
}
__device__ __forceinline__ float wave_max(float v) {
  #pragma unroll
  for (int m = 32; m; m >>= 1) v = fmaxf(v, __shfl_xor(v, m, 64));
  return v;
}

// ---- transpose WQ, WK (512x512) into ws so later GEMM-ish kernels read coalesced ----
__global__ __launch_bounds__(256) void transpose_k(const float* __restrict__ WQ,
    const float* __restrict__ WK, float* __restrict__ wqt, float* __restrict__ wkt) {
  const float* src = blockIdx.z ? WK : WQ;
  float* dst = blockIdx.z ? wkt : wqt;
  __shared__ float tile[32][33];
  int tx = threadIdx.x, ty = threadIdx.y;
  int x = blockIdx.x * 32 + tx;
  int y0 = blockIdx.y * 32;
  for (int r = ty; r < 32; r += 8) tile[r][tx] = src[(size_t)(y0 + r) * 512 + x];
  __syncthreads();
  int xo = y0 + tx;
  int yo0 = blockIdx.x * 32;
  for (int r = ty; r < 32; r += 8) dst[(size_t)(yo0 + r) * 512 + xo] = tile[tx][r];
}

// ---- wv_mean[m] = mean_d WV[m][d]; bv_mean = mean(bV) ----
__global__ __launch_bounds__(256) void wvmean_k(const float* __restrict__ WV,
    const float* __restrict__ bV, float* __restrict__ wvmean, float* __restrict__ bvout) {
  int t = threadIdx.x, w = t >> 6, lane = t & 63;
  const float4* W4 = (const float4*)WV;
  int mbase = (blockIdx.x * 4 + w) * 16;
  for (int i = 0; i < 16; ++i) {
    int m = mbase + i;
    float4 a = W4[(size_t)m * 128 + lane];
    float4 c = W4[(size_t)m * 128 + 64 + lane];
    float s = ((a.x + a.y) + (a.z + a.w)) + ((c.x + c.y) + (c.z + c.w));
    s = wave_sum(s);
    if (lane == 0) wvmean[m] = s * (1.0f / 512.0f);
  }
  if (blockIdx.x == 0 && w == 0) {
    const float4* b4 = (const float4*)bV;
    float4 a = b4[lane], c = b4[64 + lane];
    float s = ((a.x + a.y) + (a.z + a.w)) + ((c.x + c.y) + (c.z + c.w));
    s = wave_sum(s);
    if (lane == 0) bvout[0] = s * (1.0f / 512.0f);
  }
}

// ---- generic: out[b][j][:] = row(b,j) @ W + bias ; optional aux[b][j] = out_row . avec ----
// rows: if idx != null, row = src[b][idx[b*45+j]][:] (src is [B][L][512]);
//       else row = src[(b*45+j)][:]
__global__ __launch_bounds__(512) void rows_matmul_k(const float* __restrict__ src,
    const int* __restrict__ idx, const float* __restrict__ W, const float* __restrict__ bias,
    const float* __restrict__ avec, float* __restrict__ aux, float* __restrict__ out) {
  int blk = blockIdx.x;
  int b = blk / 9, g = blk % 9;
  int j0 = g * 5;
  int t = threadIdx.x;
  __shared__ float rows[5][512];
  for (int r = 0; r < 5; ++r) {
    int j = j0 + r;
    const float* s = idx ? (src + ((size_t)b * L_ + idx[b * U_ + j]) * 512)
                         : (src + ((size_t)(b * U_ + j)) * 512);
    rows[r][t] = s[t];
  }
  __syncthreads();
  float bi = bias ? bias[t] : 0.0f;
  float a0 = bi, a1 = bi, a2 = bi, a3 = bi, a4 = bi;
  #pragma unroll 4
  for (int m = 0; m < 512; ++m) {
    float wv = W[(size_t)m * 512 + t];
    a0 = fmaf(rows[0][m], wv, a0);
    a1 = fmaf(rows[1][m], wv, a1);
    a2 = fmaf(rows[2][m], wv, a2);
    a3 = fmaf(rows[3][m], wv, a3);
    a4 = fmaf(rows[4][m], wv, a4);
  }
  out[((size_t)(b * U_ + j0 + 0)) * 512 + t] = a0;
  out[((size_t)(b * U_ + j0 + 1)) * 512 + t] = a1;
  out[((size_t)(b * U_ + j0 + 2)) * 512 + t] = a2;
  out[((size_t)(b * U_ + j0 + 3)) * 512 + t] = a3;
  out[((size_t)(b * U_ + j0 + 4)) * 512 + t] = a4;
  if (avec) {
    float av = avec[t];
    __shared__ float red[8];
    float accs[5] = {a0, a1, a2, a3, a4};
    #pragma unroll
    for (int r = 0; r < 5; ++r) {
      float v = wave_sum(accs[r] * av);
      if ((t & 63) == 0) red[t >> 6] = v;
      __syncthreads();
      if (t == 0) {
        float s2 = 0.0f;
        #pragma unroll
        for (int k2 = 0; k2 < 8; ++k2) s2 += red[k2];
        aux[b * U_ + j0 + r] = s2;
      }
      __syncthreads();
    }
  }
}

// ---- meas[l] = max_j(sbar) - mean_j(sbar); sbar[l][j] = Q[l].kw[j] + c[j] ----
__global__ __launch_bounds__(256) void meas_k(const float* __restrict__ Q,
    const float* __restrict__ kw, const float* __restrict__ cvec, float* __restrict__ meas) {
  int b = blockIdx.y, tile = blockIdx.x;
  int l0 = tile * 16;
  int t = threadIdx.x, w = t >> 6, lane = t & 63;
  __shared__ float4 qt[2048];           // 16 rows x 128 float4 = 32 KB
  const float4* Q4 = (const float4*)(Q + (size_t)b * L_ * 512);
  #pragma unroll
  for (int p = 0; p < 8; ++p) qt[t + p * 256] = Q4[(size_t)l0 * 128 + t + p * 256];
  int jw0 = w * 12;                      // waves: 12,12,12,9 j's
  const float4* kw4 = (const float4*)(kw + (size_t)b * U_ * 512);
  float4 ka[12], kb[12]; float cj[12];
  #pragma unroll
  for (int jj = 0; jj < 12; ++jj) {
    int j = jw0 + jj; int jc = j < U_ ? j : U_ - 1;
    ka[jj] = kw4[jc * 128 + lane];
    kb[jj] = kw4[jc * 128 + 64 + lane];
    cj[jj] = (j < U_) ? cvec[b * U_ + j] : 0.0f;
  }
  __syncthreads();
  __shared__ float pmax[16][4], psum[16][4];
  #pragma unroll 1
  for (int r = 0; r < 16; ++r) {
    float4 qa = qt[r * 128 + lane];
    float4 qb = qt[r * 128 + 64 + lane];
    float rmax = -3.4e38f, rsum = 0.0f;
    #pragma unroll
    for (int jj = 0; jj < 12; ++jj) {
      if (jw0 + jj < U_) {
        float s = qa.x * ka[jj].x + qa.y * ka[jj].y + qa.z * ka[jj].z + qa.w * ka[jj].w
                + qb.x * kb[jj].x + qb.y * kb[jj].y + qb.z * kb[jj].z + qb.w * kb[jj].w;
        s = wave_sum(s);
        s += cj[jj];
        rmax = fmaxf(rmax, s);
        rsum += s;
      }
    }
    if (lane == 0) { pmax[r][w] = rmax; psum[r][w] = rsum; }
  }
  __syncthreads();
  if (t < 16) {
    float mx = fmaxf(fmaxf(pmax[t][0], pmax[t][1]), fmaxf(pmax[t][2], pmax[t][3]));
    float sm = psum[t][0] + psum[t][1] + psum[t][2] + psum[t][3];
    meas[(size_t)b * L_ + l0 + t] = mx - sm * (1.0f / 45.0f);
  }
}

// ---- top-45 indices per batch (iterative argmax; ties -> lower index, like lax.top_k) ----
__global__ __launch_bounds__(256) void topk_k(const float* __restrict__ meas, int* __restrict__ topI) {
  int b = blockIdx.x, t = threadIdx.x;
  __shared__ unsigned long long keys[4096];
  __shared__ unsigned long long wred[4];
  for (int i = t; i < 4096; i += 256) {
    float m = meas[(size_t)b * 4096 + i];
    unsigned u = __float_as_uint(m);
    u = (u & 0x80000000u) ? ~u : (u | 0x80000000u);   // orderable mapping
    keys[i] = ((unsigned long long)u << 32) | (unsigned)(4095 - i);
  }
  __syncthreads();
  for (int it = 0; it < U_; ++it) {
    unsigned long long lm = 0ull;
    for (int i = t; i < 4096; i += 256) { unsigned long long k = keys[i]; lm = k > lm ? k : lm; }
    #pragma unroll
    for (int m = 32; m; m >>= 1) { unsigned long long o = __shfl_xor(lm, m, 64); lm = o > lm ? o : lm; }
    if ((t & 63) == 0) wred[t >> 6] = lm;
    __syncthreads();
    if (t == 0) {
      unsigned long long f = wred[0];
      for (int k2 = 1; k2 < 4; ++k2) f = wred[k2] > f ? wred[k2] : f;
      int idxl = 4095 - (int)(f & 0xFFFFFFFFull);
      topI[b * U_ + it] = idxl;
      keys[idxl] = 0ull;
    }
    __syncthreads();
  }
}

// ---- scores[b][i][l] = (K[l].qw[i] + d[i]) * SCALE ----
__global__ __launch_bounds__(256) void scores_k(const float* __restrict__ K,
    const float* __restrict__ qw, const float* __restrict__ dvec, float* __restrict__ sc) {
  int b = blockIdx.y, tile = blockIdx.x;
  int l0 = tile * 16;
  int t = threadIdx.x, w = t >> 6, lane = t & 63;
  __shared__ float4 kt[2048];
  const float4* K4 = (const float4*)(K + (size_t)b * L_ * 512);
  #pragma unroll
  for (int p = 0; p < 8; ++p) kt[t + p * 256] = K4[(size_t)l0 * 128 + t + p * 256];
  int jw0 = w * 12;
  const float4* qw4 = (const float4*)(qw + (size_t)b * U_ * 512);
  float4 qa_[12], qb_[12]; float dj[12];
  #pragma unroll
  for (int jj = 0; jj < 12; ++jj) {
    int j = jw0 + jj; int jc = j < U_ ? j : U_ - 1;
    qa_[jj] = qw4[jc * 128 + lane];
    qb_[jj] = qw4[jc * 128 + 64 + lane];
    dj[jj] = (j < U_) ? dvec[b * U_ + j] : 0.0f;
  }
  __syncthreads();
  #pragma unroll 1
  for (int r = 0; r < 16; ++r) {
    float4 ca = kt[r * 128 + lane];
    float4 cb = kt[r * 128 + 64 + lane];
    #pragma unroll
    for (int jj = 0; jj < 12; ++jj) {
      if (jw0 + jj < U_) {
        float s = ca.x * qa_[jj].x + ca.y * qa_[jj].y + ca.z * qa_[jj].z + ca.w * qa_[jj].w
                + cb.x * qb_[jj].x + cb.y * qb_[jj].y + cb.z * qb_[jj].z + cb.w * qb_[jj].w;
        s = wave_sum(s);
        s = (s + dj[jj]) * SCALE_;
        if (lane == 0) sc[((size_t)(b * U_ + jw0 + jj)) * 4096 + l0 + r] = s;
      }
    }
  }
}

// ---- softmax in place over each score row of 4096 ----
__global__ __launch_bounds__(256) void softmax_k(float* __restrict__ sc) {
  int row = blockIdx.x;
  int t = threadIdx.x;
  float* s = sc + (size_t)row * 4096;
  __shared__ float buf[4096];
  __shared__ float red[4];
  float4* b4 = (float4*)buf;
  float4* s4 = (float4*)s;
  float lmax = -3.4e38f;
  for (int i = t; i < 1024; i += 256) {
    float4 v = s4[i]; b4[i] = v;
    lmax = fmaxf(lmax, fmaxf(fmaxf(v.x, v.y), fmaxf(v.z, v.w)));
  }
  lmax = wave_max(lmax);
  if ((t & 63) == 0) red[t >> 6] = lmax;
  __syncthreads();
  float mx = fmaxf(fmaxf(red[0], red[1]), fmaxf(red[2], red[3]));
  __syncthreads();
  float lsum = 0.0f;
  for (int i = t; i < 1024; i += 256) {
    float4 v = b4[i];
    v.x = expf(v.x - mx); v.y = expf(v.y - mx); v.z = expf(v.z - mx); v.w = expf(v.w - mx);
    b4[i] = v;
    lsum += (v.x + v.y) + (v.z + v.w);
  }
  lsum = wave_sum(lsum);
  if ((t & 63) == 0) red[t >> 6] = lsum;
  __syncthreads();
  float inv = 1.0f / (red[0] + red[1] + red[2] + red[3]);
  for (int i = t; i < 1024; i += 256) {
    float4 v = b4[i];
    v.x *= inv; v.y *= inv; v.z *= inv; v.w *= inv;
    s4[i] = v;
  }
}

// ---- partial attnV: part[ls][b][i][d] = sum over ls's l-range of attn[i][l]*V[l][d] ----
__global__ __launch_bounds__(256) void attnv_k(const float* __restrict__ V,
    const float* __restrict__ attn, float* __restrict__ part) {
  int dc = blockIdx.x, ls = blockIdx.y, b = blockIdx.z;
  int t = threadIdx.x, lq = t >> 6, dlane = t & 63;
  int dout = dc * 64 + dlane;
  __shared__ float albuf[45 * 64];
  __shared__ float parts[4][45 * 64];
  float acc[45];
  #pragma unroll
  for (int i = 0; i < 45; ++i) acc[i] = 0.0f;
  const float* Vb = V + (size_t)b * L_ * 512;
  const float* attnb = attn + (size_t)b * U_ * 4096;
  for (int lc = 0; lc < 8; ++lc) {
    int lbase = ls * 512 + lc * 64;
    __syncthreads();
    for (int idx2 = t; idx2 < 45 * 64; idx2 += 256) {
      int i = idx2 >> 6, ll = idx2 & 63;
      albuf[idx2] = attnb[(size_t)i * 4096 + lbase + ll];
    }
    __syncthreads();
    for (int k = 0; k < 16; ++k) {
      int ll = lq * 16 + k;
      float v = Vb[(size_t)(lbase + ll) * 512 + dout];
      #pragma unroll
      for (int i = 0; i < 45; ++i) acc[i] = fmaf(albuf[i * 64 + ll], v, acc[i]);
    }
  }
  __syncthreads();
  #pragma unroll
  for (int i = 0; i < 45; ++i) parts[lq][i * 64 + dlane] = acc[i];
  __syncthreads();
  for (int idx2 = t; idx2 < 45 * 64; idx2 += 256) {
    float s = parts[0][idx2] + parts[1][idx2] + parts[2][idx2] + parts[3][idx2];
    int i = idx2 >> 6, dl = idx2 & 63;
    part[(((size_t)ls * 8 + b) * U_ + i) * 512 + dc * 64 + dl] = s;
  }
}

__global__ __launch_bounds__(256) void attnvred_k(const float* __restrict__ part,
                                                  float* __restrict__ av) {
  int x = blockIdx.x * 256 + threadIdx.x;  // 184320 total
  float s = 0.0f;
  #pragma unroll
  for (int ls = 0; ls < 8; ++ls) s += part[(size_t)ls * 184320 + x];
  av[x] = s;
}

// ---- output: base fill (row-mean of Vp) + scatter s1 rows at topI ----
__global__ __launch_bounds__(256) void output_k(const float* __restrict__ V,
    const float* __restrict__ wvmean, const float* __restrict__ bvp,
    const int* __restrict__ topI, const float* __restrict__ s1, float* __restrict__ outp) {
  int b = blockIdx.y, tile = blockIdx.x;
  int l0 = tile * 64;
  int t = threadIdx.x, w = t >> 6, lane = t & 63;
  __shared__ int sel[64];
  if (t < 64) sel[t] = -1;
  __syncthreads();
  if (t < U_) {
    int lj = topI[b * U_ + t] - l0;
    if (lj >= 0 && lj < 64) sel[lj] = t;
  }
  __syncthreads();
  const float4* wv4 = (const float4*)wvmean;
  float4 wa = wv4[lane], wb = wv4[64 + lane];
  float bv = bvp[0];
  const float4* V4 = (const float4*)(V + (size_t)b * L_ * 512);
  float4* out4 = (float4*)(outp + (size_t)b * L_ * 512);
  const float4* s14 = (const float4*)s1;
  for (int r = w; r < 64; r += 4) {
    int l = l0 + r;
    int j = sel[r];
    float4 o1, o2;
    if (j >= 0) {
      o1 = s14[((size_t)(b * U_ + j)) * 128 + lane];
      o2 = s14[((size_t)(b * U_ + j)) * 128 + 64 + lane];
    } else {
      float4 va = V4[(size_t)l * 128 + lane];
      float4 vb = V4[(size_t)l * 128 + 64 + lane];
      float s = va.x * wa.x + va.y * wa.y + va.z * wa.z + va.w * wa.w
              + vb.x * wb.x + vb.y * wb.y + vb.z * wb.z + vb.w * wb.w;
      s = wave_sum(s);
      float base = s + bv;
      o1 = make_float4(base, base, base, base);
      o2 = o1;
    }
    out4[(size_t)l * 128 + lane] = o1;
    out4[(size_t)l * 128 + 64 + lane] = o2;
  }
}

extern "C" void kernel_launch(void* const* d_in, const int* in_sizes, int n_in,
                              void* d_out, int out_size, void* d_ws, size_t ws_size,
                              hipStream_t stream) {
  (void)in_sizes; (void)n_in; (void)out_size; (void)ws_size;
  const float* Q  = (const float*)d_in[0];
  const float* K  = (const float*)d_in[1];
  const float* V  = (const float*)d_in[2];
  const float* WQ = (const float*)d_in[3];
  const float* bQ = (const float*)d_in[4];
  const float* WK = (const float*)d_in[5];
  const float* bK = (const float*)d_in[6];
  const float* WV = (const float*)d_in[7];
  const float* bV = (const float*)d_in[8];
  const int* kidx = (const int*)d_in[9];
  float* ws = (float*)d_ws;
  float* out = (float*)d_out;

  float* wvmean = ws + OFF_WVMEAN;
  float* bvm    = ws + OFF_BV;
  float* wqt    = ws + OFF_WQT;
  float* wkt    = ws + OFF_WKT;
  float* kbar   = ws + OFF_KBAR;
  float* kw     = ws + OFF_KW;
  float* cvec   = ws + OFF_CVEC;
  float* measp  = ws + OFF_MEAS;
  int*   topI   = (int*)(ws + OFF_TOPI);
  float* qbar   = ws + OFF_QBAR;
  float* qw     = ws + OFF_QW;
  float* dvec   = ws + OFF_DVEC;
  float* sc     = ws + OFF_SC;
  float* partp  = ws + OFF_PART;
  float* attnv  = ws + OFF_ATTNV;
  float* s1     = ws + OFF_S1;

  // one-time weight prep
  transpose_k<<<dim3(16, 16, 2), dim3(32, 8), 0, stream>>>(WQ, WK, wqt, wkt);
  wvmean_k<<<dim3(8), dim3(256), 0, stream>>>(WV, bV, wvmean, bvm);

  // kbar = K[kidx] @ WK + bK ; c = kbar . bQ
  rows_matmul_k<<<dim3(72), dim3(512), 0, stream>>>(K, kidx, WK, bK, bQ, cvec, kbar);
  // kw = kbar @ WQ^T
  rows_matmul_k<<<dim3(72), dim3(512), 0, stream>>>(kbar, nullptr, wqt, nullptr, nullptr, nullptr, kw);
  // meas over all queries (reads Q once)
  meas_k<<<dim3(256, 8), dim3(256), 0, stream>>>(Q, kw, cvec, measp);
  // top-45 per batch
  topk_k<<<dim3(8), dim3(256), 0, stream>>>(measp, topI);
  // qbar = Q[topI] @ WQ + bQ ; d = qbar . bK
  rows_matmul_k<<<dim3(72), dim3(512), 0, stream>>>(Q, topI, WQ, bQ, bK, dvec, qbar);
  // qw = qbar @ WK^T
  rows_matmul_k<<<dim3(72), dim3(512), 0, stream>>>(qbar, nullptr, wkt, nullptr, nullptr, nullptr, qw);
  // scores (reads K once)
  scores_k<<<dim3(256, 8), dim3(256), 0, stream>>>(K, qw, dvec, sc);
  // softmax rows in place
  softmax_k<<<dim3(360), dim3(256), 0, stream>>>(sc);
  // attnV = attn @ V (partials over l-splits, then reduce)
  attnv_k<<<dim3(8, 8, 8), dim3(256), 0, stream>>>(V, sc, partp);
  attnvred_k<<<dim3(720), dim3(256), 0, stream>>>(partp, attnv);
  // s1 = attnV @ WV + bV
  rows_matmul_k<<<dim3(72), dim3(512), 0, stream>>>(attnv, nullptr, WV, bV, nullptr, nullptr, s1);
  // base fill + scatter
  output_k<<<dim3(64, 8), dim3(256), 0, stream>>>(V, wvmean, bvm, topI, s1, out);
}

// Round 2
// 539.983 us; speedup vs baseline: 1.3260x; 1.3260x over previous
//
#include <hip/hip_runtime.h>
#include <math.h>

static constexpr int B_ = 8;
static constexpr int L_ = 4096;
static constexpr int D_ = 512;
static constexpr int U_ = 45;
static constexpr float SCALE_ = 0.04419417382415922f; // 1/sqrt(512)

// ---- workspace layout (offsets in floats) ----
static constexpr size_t OFF_WVMEAN = 0;                      // 512
static constexpr size_t OFF_BV     = 512;                    // 64
static constexpr size_t OFF_WQT    = 576;                    // 512*512
static constexpr size_t OFF_WKT    = OFF_WQT + 262144;       // 512*512
static constexpr size_t OFF_KBAR   = OFF_WKT + 262144;       // 8*45*512
static constexpr size_t OFF_KW     = OFF_KBAR + 184320;      // 8*45*512
static constexpr size_t OFF_CVEC   = OFF_KW + 184320;        // 384
static constexpr size_t OFF_MEAS   = OFF_CVEC + 384;         // 8*4096
static constexpr size_t OFF_TOPI   = OFF_MEAS + 32768;       // 384 (ints)
static constexpr size_t OFF_QBAR   = OFF_TOPI + 384;         // 8*45*512
static constexpr size_t OFF_QW     = OFF_QBAR + 184320;      // 8*45*512
static constexpr size_t OFF_DVEC   = OFF_QW + 184320;        // 384
static constexpr size_t OFF_SC     = OFF_DVEC + 384;         // 8*45*4096
static constexpr size_t OFF_PART   = OFF_SC + 1474560;       // 8*(8*45*512)
static constexpr size_t OFF_ATTNV  = OFF_PART + 1474560;     // 8*45*512
static constexpr size_t OFF_S1     = OFF_ATTNV + 184320;     // 8*45*512

__device__ __forceinline__ float wave_sum(float v) {
  #pragma unroll
  for (int m = 32; m; m >>= 1) v += __shfl_xor(v, m, 64);
  return v;
}
__device__ __forceinline__ float wave_max(float v) {
  #pragma unroll
  for (int m = 32; m; m >>= 1) v = fmaxf(v, __shfl_xor(v, m, 64));
  return v;
}

// ---- transpose WQ, WK (512x512) into ws so later GEMM-ish kernels read coalesced ----
__global__ __launch_bounds__(256) void transpose_k(const float* __restrict__ WQ,
    const float* __restrict__ WK, float* __restrict__ wqt, float* __restrict__ wkt) {
  const float* src = blockIdx.z ? WK : WQ;
  float* dst = blockIdx.z ? wkt : wqt;
  __shared__ float tile[32][33];
  int tx = threadIdx.x, ty = threadIdx.y;
  int x = blockIdx.x * 32 + tx;
  int y0 = blockIdx.y * 32;
  for (int r = ty; r < 32; r += 8) tile[r][tx] = src[(size_t)(y0 + r) * 512 + x];
  __syncthreads();
  int xo = y0 + tx;
  int yo0 = blockIdx.x * 32;
  for (int r = ty; r < 32; r += 8) dst[(size_t)(yo0 + r) * 512 + xo] = tile[tx][r];
}

// ---- wv_mean[m] = mean_d WV[m][d]; bv_mean = mean(bV) ----
__global__ __launch_bounds__(256) void wvmean_k(const float* __restrict__ WV,
    const float* __restrict__ bV, float* __restrict__ wvmean, float* __restrict__ bvout) {
  int t = threadIdx.x, w = t >> 6, lane = t & 63;
  const float4* W4 = (const float4*)WV;
  int mbase = (blockIdx.x * 4 + w) * 16;
  for (int i = 0; i < 16; ++i) {
    int m = mbase + i;
    float4 a = W4[(size_t)m * 128 + lane];
    float4 c = W4[(size_t)m * 128 + 64 + lane];
    float s = ((a.x + a.y) + (a.z + a.w)) + ((c.x + c.y) + (c.z + c.w));
    s = wave_sum(s);
    if (lane == 0) wvmean[m] = s * (1.0f / 512.0f);
  }
  if (blockIdx.x == 0 && w == 0) {
    const float4* b4 = (const float4*)bV;
    float4 a = b4[lane], c = b4[64 + lane];
    float s = ((a.x + a.y) + (a.z + a.w)) + ((c.x + c.y) + (c.z + c.w));
    s = wave_sum(s);
    if (lane == 0) bvout[0] = s * (1.0f / 512.0f);
  }
}

// ---- generic: out[b][j][:] = row(b,j) @ W + bias ; optional aux[b][j] = out_row . avec ----
__global__ __launch_bounds__(512) void rows_matmul_k(const float* __restrict__ src,
    const int* __restrict__ idx, const float* __restrict__ W, const float* __restrict__ bias,
    const float* __restrict__ avec, float* __restrict__ aux, float* __restrict__ out) {
  int blk = blockIdx.x;
  int b = blk / 9, g = blk % 9;
  int j0 = g * 5;
  int t = threadIdx.x;
  __shared__ float rows[5][512];
  for (int r = 0; r < 5; ++r) {
    int j = j0 + r;
    const float* s = idx ? (src + ((size_t)b * L_ + idx[b * U_ + j]) * 512)
                         : (src + ((size_t)(b * U_ + j)) * 512);
    rows[r][t] = s[t];
  }
  __syncthreads();
  float bi = bias ? bias[t] : 0.0f;
  float a0 = bi, a1 = bi, a2 = bi, a3 = bi, a4 = bi;
  #pragma unroll 4
  for (int m = 0; m < 512; ++m) {
    float wv = W[(size_t)m * 512 + t];
    a0 = fmaf(rows[0][m], wv, a0);
    a1 = fmaf(rows[1][m], wv, a1);
    a2 = fmaf(rows[2][m], wv, a2);
    a3 = fmaf(rows[3][m], wv, a3);
    a4 = fmaf(rows[4][m], wv, a4);
  }
  out[((size_t)(b * U_ + j0 + 0)) * 512 + t] = a0;
  out[((size_t)(b * U_ + j0 + 1)) * 512 + t] = a1;
  out[((size_t)(b * U_ + j0 + 2)) * 512 + t] = a2;
  out[((size_t)(b * U_ + j0 + 3)) * 512 + t] = a3;
  out[((size_t)(b * U_ + j0 + 4)) * 512 + t] = a4;
  if (avec) {
    float av = avec[t];
    __shared__ float red[8];
    float accs[5] = {a0, a1, a2, a3, a4};
    #pragma unroll
    for (int r = 0; r < 5; ++r) {
      float v = wave_sum(accs[r] * av);
      if ((t & 63) == 0) red[t >> 6] = v;
      __syncthreads();
      if (t == 0) {
        float s2 = 0.0f;
        #pragma unroll
        for (int k2 = 0; k2 < 8; ++k2) s2 += red[k2];
        aux[b * U_ + j0 + r] = s2;
      }
      __syncthreads();
    }
  }
}

// ==== register-blocked GEMM for meas: S = Q_tile[128x512] @ kw^T[512x48] ====
// grid (32, 8), block 256 = 16 tx (3 j each) x 16 ty (8 l each)
__global__ __launch_bounds__(256) void meas2_k(const float* __restrict__ Q,
    const float* __restrict__ kw, const float* __restrict__ cvec, float* __restrict__ meas) {
  const int b = blockIdx.y;
  const int l0 = blockIdx.x * 128;
  const int t = threadIdx.x;
  const int tx = t & 15, ty = t >> 4;
  const int rswz = ty & 3;

  __shared__ float Qs[128][68];
  __shared__ float Ks[48][68];

  float acc[8][3];
  #pragma unroll
  for (int i = 0; i < 8; ++i) { acc[i][0] = 0.f; acc[i][1] = 0.f; acc[i][2] = 0.f; }

  const float4* Q4  = (const float4*)(Q + ((size_t)b * L_ + l0) * 512);
  const float4* kw4 = (const float4*)(kw + (size_t)b * U_ * 512);

  // prefetch registers
  float4 pq[8], pk[3];
  int lr[8], lc[8], kr[3], kc[3];
  #pragma unroll
  for (int p = 0; p < 8; ++p) { int idx = p * 256 + t; lr[p] = idx >> 4; lc[p] = idx & 15; }
  #pragma unroll
  for (int p = 0; p < 3; ++p) { int idx = p * 256 + t; kr[p] = idx >> 4; kc[p] = idx & 15; }

  #pragma unroll
  for (int p = 0; p < 8; ++p) pq[p] = Q4[(size_t)lr[p] * 128 + lc[p]];
  #pragma unroll
  for (int p = 0; p < 3; ++p)
    pk[p] = (kr[p] < U_) ? kw4[(size_t)kr[p] * 128 + kc[p]] : make_float4(0.f, 0.f, 0.f, 0.f);

  #pragma unroll
  for (int p = 0; p < 8; ++p) {
    int sw = (lr[p] >> 3) & 3;
    *(float4*)&Qs[lr[p]][(lc[p] ^ sw) * 4] = pq[p];
  }
  #pragma unroll
  for (int p = 0; p < 3; ++p) *(float4*)&Ks[kr[p]][kc[p] * 4] = pk[p];
  __syncthreads();

  for (int it = 0; it < 8; ++it) {
    if (it < 7) {
      int k0 = (it + 1) * 16;
      #pragma unroll
      for (int p = 0; p < 8; ++p) pq[p] = Q4[(size_t)lr[p] * 128 + k0 + lc[p]];
      #pragma unroll
      for (int p = 0; p < 3; ++p)
        pk[p] = (kr[p] < U_) ? kw4[(size_t)kr[p] * 128 + k0 + kc[p]] : make_float4(0.f, 0.f, 0.f, 0.f);
    }
    #pragma unroll 4
    for (int kk4 = 0; kk4 < 16; ++kk4) {
      float4 kv0 = *(const float4*)&Ks[tx * 3 + 0][kk4 * 4];
      float4 kv1 = *(const float4*)&Ks[tx * 3 + 1][kk4 * 4];
      float4 kv2 = *(const float4*)&Ks[tx * 3 + 2][kk4 * 4];
      int qc = (kk4 ^ rswz) * 4;
      #pragma unroll
      for (int i = 0; i < 8; ++i) {
        float4 qv = *(const float4*)&Qs[ty * 8 + i][qc];
        acc[i][0] = fmaf(qv.x, kv0.x, acc[i][0]); acc[i][0] = fmaf(qv.y, kv0.y, acc[i][0]);
        acc[i][0] = fmaf(qv.z, kv0.z, acc[i][0]); acc[i][0] = fmaf(qv.w, kv0.w, acc[i][0]);
        acc[i][1] = fmaf(qv.x, kv1.x, acc[i][1]); acc[i][1] = fmaf(qv.y, kv1.y, acc[i][1]);
        acc[i][1] = fmaf(qv.z, kv1.z, acc[i][1]); acc[i][1] = fmaf(qv.w, kv1.w, acc[i][1]);
        acc[i][2] = fmaf(qv.x, kv2.x, acc[i][2]); acc[i][2] = fmaf(qv.y, kv2.y, acc[i][2]);
        acc[i][2] = fmaf(qv.z, kv2.z, acc[i][2]); acc[i][2] = fmaf(qv.w, kv2.w, acc[i][2]);
      }
    }
    __syncthreads();
    if (it < 7) {
      #pragma unroll
      for (int p = 0; p < 8; ++p) {
        int sw = (lr[p] >> 3) & 3;
        *(float4*)&Qs[lr[p]][(lc[p] ^ sw) * 4] = pq[p];
      }
      #pragma unroll
      for (int p = 0; p < 3; ++p) *(float4*)&Ks[kr[p]][kc[p] * 4] = pk[p];
      __syncthreads();
    }
  }

  // add cvec and reduce max/sum over j (across the 16 tx lanes)
  const bool valid = (tx < 15);
  float c0 = 0.f, c1 = 0.f, c2 = 0.f;
  if (valid) {
    c0 = cvec[b * U_ + tx * 3 + 0];
    c1 = cvec[b * U_ + tx * 3 + 1];
    c2 = cvec[b * U_ + tx * 3 + 2];
  }
  #pragma unroll
  for (int i = 0; i < 8; ++i) {
    float s0 = acc[i][0] + c0, s1 = acc[i][1] + c1, s2 = acc[i][2] + c2;
    float jmax = valid ? fmaxf(fmaxf(s0, s1), s2) : -3.4e38f;
    float jsum = valid ? (s0 + s1 + s2) : 0.f;
    #pragma unroll
    for (int m = 8; m; m >>= 1) {
      jmax = fmaxf(jmax, __shfl_xor(jmax, m, 64));
      jsum += __shfl_xor(jsum, m, 64);
    }
    if (tx == 0) meas[(size_t)b * L_ + l0 + ty * 8 + i] = jmax - jsum * (1.0f / 45.0f);
  }
}

// ==== same GEMM for scores: sc[b][j][l] = (K[l].qw[j] + d[j]) * SCALE ====
__global__ __launch_bounds__(256) void scores2_k(const float* __restrict__ K,
    const float* __restrict__ qw, const float* __restrict__ dvec, float* __restrict__ sc) {
  const int b = blockIdx.y;
  const int l0 = blockIdx.x * 128;
  const int t = threadIdx.x;
  const int tx = t & 15, ty = t >> 4;
  const int rswz = ty & 3;

  __shared__ float Qs[128][68];   // K-tile
  __shared__ float Ks[48][68];    // qw rows

  float acc[8][3];
  #pragma unroll
  for (int i = 0; i < 8; ++i) { acc[i][0] = 0.f; acc[i][1] = 0.f; acc[i][2] = 0.f; }

  const float4* K4  = (const float4*)(K + ((size_t)b * L_ + l0) * 512);
  const float4* qw4 = (const float4*)(qw + (size_t)b * U_ * 512);

  float4 pq[8], pk[3];
  int lr[8], lc[8], kr[3], kc[3];
  #pragma unroll
  for (int p = 0; p < 8; ++p) { int idx = p * 256 + t; lr[p] = idx >> 4; lc[p] = idx & 15; }
  #pragma unroll
  for (int p = 0; p < 3; ++p) { int idx = p * 256 + t; kr[p] = idx >> 4; kc[p] = idx & 15; }

  #pragma unroll
  for (int p = 0; p < 8; ++p) pq[p] = K4[(size_t)lr[p] * 128 + lc[p]];
  #pragma unroll
  for (int p = 0; p < 3; ++p)
    pk[p] = (kr[p] < U_) ? qw4[(size_t)kr[p] * 128 + kc[p]] : make_float4(0.f, 0.f, 0.f, 0.f);

  #pragma unroll
  for (int p = 0; p < 8; ++p) {
    int sw = (lr[p] >> 3) & 3;
    *(float4*)&Qs[lr[p]][(lc[p] ^ sw) * 4] = pq[p];
  }
  #pragma unroll
  for (int p = 0; p < 3; ++p) *(float4*)&Ks[kr[p]][kc[p] * 4] = pk[p];
  __syncthreads();

  for (int it = 0; it < 8; ++it) {
    if (it < 7) {
      int k0 = (it + 1) * 16;
      #pragma unroll
      for (int p = 0; p < 8; ++p) pq[p] = K4[(size_t)lr[p] * 128 + k0 + lc[p]];
      #pragma unroll
      for (int p = 0; p < 3; ++p)
        pk[p] = (kr[p] < U_) ? qw4[(size_t)kr[p] * 128 + k0 + kc[p]] : make_float4(0.f, 0.f, 0.f, 0.f);
    }
    #pragma unroll 4
    for (int kk4 = 0; kk4 < 16; ++kk4) {
      float4 kv0 = *(const float4*)&Ks[tx * 3 + 0][kk4 * 4];
      float4 kv1 = *(const float4*)&Ks[tx * 3 + 1][kk4 * 4];
      float4 kv2 = *(const float4*)&Ks[tx * 3 + 2][kk4 * 4];
      int qc = (kk4 ^ rswz) * 4;
      #pragma unroll
      for (int i = 0; i < 8; ++i) {
        float4 qv = *(const float4*)&Qs[ty * 8 + i][qc];
        acc[i][0] = fmaf(qv.x, kv0.x, acc[i][0]); acc[i][0] = fmaf(qv.y, kv0.y, acc[i][0]);
        acc[i][0] = fmaf(qv.z, kv0.z, acc[i][0]); acc[i][0] = fmaf(qv.w, kv0.w, acc[i][0]);
        acc[i][1] = fmaf(qv.x, kv1.x, acc[i][1]); acc[i][1] = fmaf(qv.y, kv1.y, acc[i][1]);
        acc[i][1] = fmaf(qv.z, kv1.z, acc[i][1]); acc[i][1] = fmaf(qv.w, kv1.w, acc[i][1]);
        acc[i][2] = fmaf(qv.x, kv2.x, acc[i][2]); acc[i][2] = fmaf(qv.y, kv2.y, acc[i][2]);
        acc[i][2] = fmaf(qv.z, kv2.z, acc[i][2]); acc[i][2] = fmaf(qv.w, kv2.w, acc[i][2]);
      }
    }
    __syncthreads();
    if (it < 7) {
      #pragma unroll
      for (int p = 0; p < 8; ++p) {
        int sw = (lr[p] >> 3) & 3;
        *(float4*)&Qs[lr[p]][(lc[p] ^ sw) * 4] = pq[p];
      }
      #pragma unroll
      for (int p = 0; p < 3; ++p) *(float4*)&Ks[kr[p]][kc[p] * 4] = pk[p];
      __syncthreads();
    }
  }

  if (tx < 15) {
    float d0 = dvec[b * U_ + tx * 3 + 0];
    float d1 = dvec[b * U_ + tx * 3 + 1];
    float d2 = dvec[b * U_ + tx * 3 + 2];
    #pragma unroll
    for (int i = 0; i < 8; ++i) {
      int l = l0 + ty * 8 + i;
      sc[((size_t)(b * U_ + tx * 3 + 0)) * 4096 + l] = (acc[i][0] + d0) * SCALE_;
      sc[((size_t)(b * U_ + tx * 3 + 1)) * 4096 + l] = (acc[i][1] + d1) * SCALE_;
      sc[((size_t)(b * U_ + tx * 3 + 2)) * 4096 + l] = (acc[i][2] + d2) * SCALE_;
    }
  }
}

// ---- top-45 indices per batch (iterative argmax; ties -> lower index) ----
__global__ __launch_bounds__(256) void topk_k(const float* __restrict__ meas, int* __restrict__ topI) {
  int b = blockIdx.x, t = threadIdx.x;
  __shared__ unsigned long long keys[4096];
  __shared__ unsigned long long wred[4];
  for (int i = t; i < 4096; i += 256) {
    float m = meas[(size_t)b * 4096 + i];
    unsigned u = __float_as_uint(m);
    u = (u & 0x80000000u) ? ~u : (u | 0x80000000u);
    keys[i] = ((unsigned long long)u << 32) | (unsigned)(4095 - i);
  }
  __syncthreads();
  for (int it = 0; it < U_; ++it) {
    unsigned long long lm = 0ull;
    for (int i = t; i < 4096; i += 256) { unsigned long long k = keys[i]; lm = k > lm ? k : lm; }
    #pragma unroll
    for (int m = 32; m; m >>= 1) { unsigned long long o = __shfl_xor(lm, m, 64); lm = o > lm ? o : lm; }
    if ((t & 63) == 0) wred[t >> 6] = lm;
    __syncthreads();
    if (t == 0) {
      unsigned long long f = wred[0];
      for (int k2 = 1; k2 < 4; ++k2) f = wred[k2] > f ? wred[k2] : f;
      int idxl = 4095 - (int)(f & 0xFFFFFFFFull);
      topI[b * U_ + it] = idxl;
      keys[idxl] = 0ull;
    }
    __syncthreads();
  }
}

// ---- softmax in place over each score row of 4096 ----
__global__ __launch_bounds__(256) void softmax_k(float* __restrict__ sc) {
  int row = blockIdx.x;
  int t = threadIdx.x;
  float* s = sc + (size_t)row * 4096;
  __shared__ float buf[4096];
  __shared__ float red[4];
  float4* b4 = (float4*)buf;
  float4* s4 = (float4*)s;
  float lmax = -3.4e38f;
  for (int i = t; i < 1024; i += 256) {
    float4 v = s4[i]; b4[i] = v;
    lmax = fmaxf(lmax, fmaxf(fmaxf(v.x, v.y), fmaxf(v.z, v.w)));
  }
  lmax = wave_max(lmax);
  if ((t & 63) == 0) red[t >> 6] = lmax;
  __syncthreads();
  float mx = fmaxf(fmaxf(red[0], red[1]), fmaxf(red[2], red[3]));
  __syncthreads();
  float lsum = 0.0f;
  for (int i = t; i < 1024; i += 256) {
    float4 v = b4[i];
    v.x = expf(v.x - mx); v.y = expf(v.y - mx); v.z = expf(v.z - mx); v.w = expf(v.w - mx);
    b4[i] = v;
    lsum += (v.x + v.y) + (v.z + v.w);
  }
  lsum = wave_sum(lsum);
  if ((t & 63) == 0) red[t >> 6] = lsum;
  __syncthreads();
  float inv = 1.0f / (red[0] + red[1] + red[2] + red[3]);
  for (int i = t; i < 1024; i += 256) {
    float4 v = b4[i];
    v.x *= inv; v.y *= inv; v.z *= inv; v.w *= inv;
    s4[i] = v;
  }
}

// ---- partial attnV ----
__global__ __launch_bounds__(256) void attnv_k(const float* __restrict__ V,
    const float* __restrict__ attn, float* __restrict__ part) {
  int dc = blockIdx.x, ls = blockIdx.y, b = blockIdx.z;
  int t = threadIdx.x, lq = t >> 6, dlane = t & 63;
  int dout = dc * 64 + dlane;
  __shared__ float albuf[45 * 64];
  __shared__ float parts[4][45 * 64];
  float acc[45];
  #pragma unroll
  for (int i = 0; i < 45; ++i) acc[i] = 0.0f;
  const float* Vb = V + (size_t)b * L_ * 512;
  const float* attnb = attn + (size_t)b * U_ * 4096;
  for (int lc = 0; lc < 8; ++lc) {
    int lbase = ls * 512 + lc * 64;
    __syncthreads();
    for (int idx2 = t; idx2 < 45 * 64; idx2 += 256) {
      int i = idx2 >> 6, ll = idx2 & 63;
      albuf[idx2] = attnb[(size_t)i * 4096 + lbase + ll];
    }
    __syncthreads();
    for (int k = 0; k < 16; ++k) {
      int ll = lq * 16 + k;
      float v = Vb[(size_t)(lbase + ll) * 512 + dout];
      #pragma unroll
      for (int i = 0; i < 45; ++i) acc[i] = fmaf(albuf[i * 64 + ll], v, acc[i]);
    }
  }
  __syncthreads();
  #pragma unroll
  for (int i = 0; i < 45; ++i) parts[lq][i * 64 + dlane] = acc[i];
  __syncthreads();
  for (int idx2 = t; idx2 < 45 * 64; idx2 += 256) {
    float s = parts[0][idx2] + parts[1][idx2] + parts[2][idx2] + parts[3][idx2];
    int i = idx2 >> 6, dl = idx2 & 63;
    part[(((size_t)ls * 8 + b) * U_ + i) * 512 + dc * 64 + dl] = s;
  }
}

__global__ __launch_bounds__(256) void attnvred_k(const float* __restrict__ part,
                                                  float* __restrict__ av) {
  int x = blockIdx.x * 256 + threadIdx.x;
  float s = 0.0f;
  #pragma unroll
  for (int ls = 0; ls < 8; ++ls) s += part[(size_t)ls * 184320 + x];
  av[x] = s;
}

// ---- output: base fill (row-mean of Vp) + scatter s1 rows at topI ----
__global__ __launch_bounds__(256) void output_k(const float* __restrict__ V,
    const float* __restrict__ wvmean, const float* __restrict__ bvp,
    const int* __restrict__ topI, const float* __restrict__ s1, float* __restrict__ outp) {
  int b = blockIdx.y, tile = blockIdx.x;
  int l0 = tile * 64;
  int t = threadIdx.x, w = t >> 6, lane = t & 63;
  __shared__ int sel[64];
  if (t < 64) sel[t] = -1;
  __syncthreads();
  if (t < U_) {
    int lj = topI[b * U_ + t] - l0;
    if (lj >= 0 && lj < 64) sel[lj] = t;
  }
  __syncthreads();
  const float4* wv4 = (const float4*)wvmean;
  float4 wa = wv4[lane], wb = wv4[64 + lane];
  float bv = bvp[0];
  const float4* V4 = (const float4*)(V + (size_t)b * L_ * 512);
  float4* out4 = (float4*)(outp + (size_t)b * L_ * 512);
  const float4* s14 = (const float4*)s1;
  for (int r = w; r < 64; r += 4) {
    int l = l0 + r;
    int j = sel[r];
    float4 o1, o2;
    if (j >= 0) {
      o1 = s14[((size_t)(b * U_ + j)) * 128 + lane];
      o2 = s14[((size_t)(b * U_ + j)) * 128 + 64 + lane];
    } else {
      float4 va = V4[(size_t)l * 128 + lane];
      float4 vb = V4[(size_t)l * 128 + 64 + lane];
      float s = va.x * wa.x + va.y * wa.y + va.z * wa.z + va.w * wa.w
              + vb.x * wb.x + vb.y * wb.y + vb.z * wb.z + vb.w * wb.w;
      s = wave_sum(s);
      float base = s + bv;
      o1 = make_float4(base, base, base, base);
      o2 = o1;
    }
    out4[(size_t)l * 128 + lane] = o1;
    out4[(size_t)l * 128 + 64 + lane] = o2;
  }
}

extern "C" void kernel_launch(void* const* d_in, const int* in_sizes, int n_in,
                              void* d_out, int out_size, void* d_ws, size_t ws_size,
                              hipStream_t stream) {
  (void)in_sizes; (void)n_in; (void)out_size; (void)ws_size;
  const float* Q  = (const float*)d_in[0];
  const float* K  = (const float*)d_in[1];
  const float* V  = (const float*)d_in[2];
  const float* WQ = (const float*)d_in[3];
  const float* bQ = (const float*)d_in[4];
  const float* WK = (const float*)d_in[5];
  const float* bK = (const float*)d_in[6];
  const float* WV = (const float*)d_in[7];
  const float* bV = (const float*)d_in[8];
  const int* kidx = (const int*)d_in[9];
  float* ws = (float*)d_ws;
  float* out = (float*)d_out;

  float* wvmean = ws + OFF_WVMEAN;
  float* bvm    = ws + OFF_BV;
  float* wqt    = ws + OFF_WQT;
  float* wkt    = ws + OFF_WKT;
  float* kbar   = ws + OFF_KBAR;
  float* kw     = ws + OFF_KW;
  float* cvec   = ws + OFF_CVEC;
  float* measp  = ws + OFF_MEAS;
  int*   topI   = (int*)(ws + OFF_TOPI);
  float* qbar   = ws + OFF_QBAR;
  float* qw     = ws + OFF_QW;
  float* dvec   = ws + OFF_DVEC;
  float* sc     = ws + OFF_SC;
  float* partp  = ws + OFF_PART;
  float* attnv  = ws + OFF_ATTNV;
  float* s1     = ws + OFF_S1;

  transpose_k<<<dim3(16, 16, 2), dim3(32, 8), 0, stream>>>(WQ, WK, wqt, wkt);
  wvmean_k<<<dim3(8), dim3(256), 0, stream>>>(WV, bV, wvmean, bvm);

  rows_matmul_k<<<dim3(72), dim3(512), 0, stream>>>(K, kidx, WK, bK, bQ, cvec, kbar);
  rows_matmul_k<<<dim3(72), dim3(512), 0, stream>>>(kbar, nullptr, wqt, nullptr, nullptr, nullptr, kw);
  meas2_k<<<dim3(32, 8), dim3(256), 0, stream>>>(Q, kw, cvec, measp);
  topk_k<<<dim3(8), dim3(256), 0, stream>>>(measp, topI);
  rows_matmul_k<<<dim3(72), dim3(512), 0, stream>>>(Q, topI, WQ, bQ, bK, dvec, qbar);
  rows_matmul_k<<<dim3(72), dim3(512), 0, stream>>>(qbar, nullptr, wkt, nullptr, nullptr, nullptr, qw);
  scores2_k<<<dim3(32, 8), dim3(256), 0, stream>>>(K, qw, dvec, sc);
  softmax_k<<<dim3(360), dim3(256), 0, stream>>>(sc);
  attnv_k<<<dim3(8, 8, 8), dim3(256), 0, stream>>>(V, sc, partp);
  attnvred_k<<<dim3(720), dim3(256), 0, stream>>>(partp, attnv);
  rows_matmul_k<<<dim3(72), dim3(512), 0, stream>>>(attnv, nullptr, WV, bV, nullptr, nullptr, s1);
  output_k<<<dim3(64, 8), dim3(256), 0, stream>>>(V, wvmean, bvm, topI, s1, out);
}

// Round 3
// 513.316 us; speedup vs baseline: 1.3948x; 1.0520x over previous
//
#include <hip/hip_runtime.h>
#include <math.h>

static constexpr int B_ = 8;
static constexpr int L_ = 4096;
static constexpr int D_ = 512;
static constexpr int U_ = 45;
static constexpr float SCALE_ = 0.04419417382415922f; // 1/sqrt(512)

// ---- workspace layout (offsets in floats) ----
static constexpr size_t OFF_WVMEAN = 0;                      // 512
static constexpr size_t OFF_BV     = 512;                    // 64
static constexpr size_t OFF_WQT    = 576;                    // 512*512
static constexpr size_t OFF_WKT    = OFF_WQT + 262144;       // 512*512
static constexpr size_t OFF_KBAR   = OFF_WKT + 262144;       // 8*45*512
static constexpr size_t OFF_KW     = OFF_KBAR + 184320;      // 8*45*512
static constexpr size_t OFF_CVEC   = OFF_KW + 184320;        // 384
static constexpr size_t OFF_MEAS   = OFF_CVEC + 384;         // 8*4096
static constexpr size_t OFF_TOPI   = OFF_MEAS + 32768;       // 384 (ints)
static constexpr size_t OFF_QBAR   = OFF_TOPI + 384;         // 8*45*512
static constexpr size_t OFF_QW     = OFF_QBAR + 184320;      // 8*45*512
static constexpr size_t OFF_DVEC   = OFF_QW + 184320;        // 384
static constexpr size_t OFF_SC     = OFF_DVEC + 384;         // 8*45*4096
static constexpr size_t OFF_PART   = OFF_SC + 1474560;       // 8 slabs * 8*45*512
static constexpr size_t OFF_ATTNV  = OFF_PART + 1474560;     // 8*45*512
static constexpr size_t OFF_S1     = OFF_ATTNV + 184320;     // 8*45*512

__device__ __forceinline__ float wave_sum(float v) {
  #pragma unroll
  for (int m = 32; m; m >>= 1) v += __shfl_xor(v, m, 64);
  return v;
}
__device__ __forceinline__ float wave_max(float v) {
  #pragma unroll
  for (int m = 32; m; m >>= 1) v = fmaxf(v, __shfl_xor(v, m, 64));
  return v;
}

// ---- transpose WQ, WK (512x512) into ws so later GEMM-ish kernels read coalesced ----
__global__ __launch_bounds__(256) void transpose_k(const float* __restrict__ WQ,
    const float* __restrict__ WK, float* __restrict__ wqt, float* __restrict__ wkt) {
  const float* src = blockIdx.z ? WK : WQ;
  float* dst = blockIdx.z ? wkt : wqt;
  __shared__ float tile[32][33];
  int tx = threadIdx.x, ty = threadIdx.y;
  int x = blockIdx.x * 32 + tx;
  int y0 = blockIdx.y * 32;
  for (int r = ty; r < 32; r += 8) tile[r][tx] = src[(size_t)(y0 + r) * 512 + x];
  __syncthreads();
  int xo = y0 + tx;
  int yo0 = blockIdx.x * 32;
  for (int r = ty; r < 32; r += 8) dst[(size_t)(yo0 + r) * 512 + xo] = tile[tx][r];
}

// ---- wv_mean[m] = mean_d WV[m][d]; bv_mean = mean(bV) ----
__global__ __launch_bounds__(256) void wvmean_k(const float* __restrict__ WV,
    const float* __restrict__ bV, float* __restrict__ wvmean, float* __restrict__ bvout) {
  int t = threadIdx.x, w = t >> 6, lane = t & 63;
  const float4* W4 = (const float4*)WV;
  int mbase = (blockIdx.x * 4 + w) * 16;
  for (int i = 0; i < 16; ++i) {
    int m = mbase + i;
    float4 a = W4[(size_t)m * 128 + lane];
    float4 c = W4[(size_t)m * 128 + 64 + lane];
    float s = ((a.x + a.y) + (a.z + a.w)) + ((c.x + c.y) + (c.z + c.w));
    s = wave_sum(s);
    if (lane == 0) wvmean[m] = s * (1.0f / 512.0f);
  }
  if (blockIdx.x == 0 && w == 0) {
    const float4* b4 = (const float4*)bV;
    float4 a = b4[lane], c = b4[64 + lane];
    float s = ((a.x + a.y) + (a.z + a.w)) + ((c.x + c.y) + (c.z + c.w));
    s = wave_sum(s);
    if (lane == 0) bvout[0] = s * (1.0f / 512.0f);
  }
}

// ---- generic: out[b][j][:] = row(b,j) @ W + bias ; optional aux[b][j] = out_row . avec ----
__global__ __launch_bounds__(512) void rows_matmul_k(const float* __restrict__ src,
    const int* __restrict__ idx, const float* __restrict__ W, const float* __restrict__ bias,
    const float* __restrict__ avec, float* __restrict__ aux, float* __restrict__ out) {
  int blk = blockIdx.x;
  int b = blk / 9, g = blk % 9;
  int j0 = g * 5;
  int t = threadIdx.x;
  __shared__ float rows[5][512];
  for (int r = 0; r < 5; ++r) {
    int j = j0 + r;
    const float* s = idx ? (src + ((size_t)b * L_ + idx[b * U_ + j]) * 512)
                         : (src + ((size_t)(b * U_ + j)) * 512);
    rows[r][t] = s[t];
  }
  __syncthreads();
  float bi = bias ? bias[t] : 0.0f;
  float a0 = bi, a1 = bi, a2 = bi, a3 = bi, a4 = bi;
  #pragma unroll 4
  for (int m = 0; m < 512; ++m) {
    float wv = W[(size_t)m * 512 + t];
    a0 = fmaf(rows[0][m], wv, a0);
    a1 = fmaf(rows[1][m], wv, a1);
    a2 = fmaf(rows[2][m], wv, a2);
    a3 = fmaf(rows[3][m], wv, a3);
    a4 = fmaf(rows[4][m], wv, a4);
  }
  out[((size_t)(b * U_ + j0 + 0)) * 512 + t] = a0;
  out[((size_t)(b * U_ + j0 + 1)) * 512 + t] = a1;
  out[((size_t)(b * U_ + j0 + 2)) * 512 + t] = a2;
  out[((size_t)(b * U_ + j0 + 3)) * 512 + t] = a3;
  out[((size_t)(b * U_ + j0 + 4)) * 512 + t] = a4;
  if (avec) {
    float av = avec[t];
    __shared__ float red[8];
    float accs[5] = {a0, a1, a2, a3, a4};
    #pragma unroll
    for (int r = 0; r < 5; ++r) {
      float v = wave_sum(accs[r] * av);
      if ((t & 63) == 0) red[t >> 6] = v;
      __syncthreads();
      if (t == 0) {
        float s2 = 0.0f;
        #pragma unroll
        for (int k2 = 0; k2 < 8; ++k2) s2 += red[k2];
        aux[b * U_ + j0 + r] = s2;
      }
      __syncthreads();
    }
  }
}

// ==== register-blocked GEMM for meas: S = Q_tile[128x512] @ kw^T[512x48] ====
__global__ __launch_bounds__(256) void meas2_k(const float* __restrict__ Q,
    const float* __restrict__ kw, const float* __restrict__ cvec, float* __restrict__ meas) {
  const int b = blockIdx.y;
  const int l0 = blockIdx.x * 128;
  const int t = threadIdx.x;
  const int tx = t & 15, ty = t >> 4;
  const int rswz = ty & 3;

  __shared__ float Qs[128][68];
  __shared__ float Ks[48][68];

  float acc[8][3];
  #pragma unroll
  for (int i = 0; i < 8; ++i) { acc[i][0] = 0.f; acc[i][1] = 0.f; acc[i][2] = 0.f; }

  const float4* Q4  = (const float4*)(Q + ((size_t)b * L_ + l0) * 512);
  const float4* kw4 = (const float4*)(kw + (size_t)b * U_ * 512);

  float4 pq[8], pk[3];
  int lr[8], lc[8], kr[3], kc[3];
  #pragma unroll
  for (int p = 0; p < 8; ++p) { int idx = p * 256 + t; lr[p] = idx >> 4; lc[p] = idx & 15; }
  #pragma unroll
  for (int p = 0; p < 3; ++p) { int idx = p * 256 + t; kr[p] = idx >> 4; kc[p] = idx & 15; }

  #pragma unroll
  for (int p = 0; p < 8; ++p) pq[p] = Q4[(size_t)lr[p] * 128 + lc[p]];
  #pragma unroll
  for (int p = 0; p < 3; ++p)
    pk[p] = (kr[p] < U_) ? kw4[(size_t)kr[p] * 128 + kc[p]] : make_float4(0.f, 0.f, 0.f, 0.f);

  #pragma unroll
  for (int p = 0; p < 8; ++p) {
    int sw = (lr[p] >> 3) & 3;
    *(float4*)&Qs[lr[p]][(lc[p] ^ sw) * 4] = pq[p];
  }
  #pragma unroll
  for (int p = 0; p < 3; ++p) *(float4*)&Ks[kr[p]][kc[p] * 4] = pk[p];
  __syncthreads();

  for (int it = 0; it < 8; ++it) {
    if (it < 7) {
      int k0 = (it + 1) * 16;
      #pragma unroll
      for (int p = 0; p < 8; ++p) pq[p] = Q4[(size_t)lr[p] * 128 + k0 + lc[p]];
      #pragma unroll
      for (int p = 0; p < 3; ++p)
        pk[p] = (kr[p] < U_) ? kw4[(size_t)kr[p] * 128 + k0 + kc[p]] : make_float4(0.f, 0.f, 0.f, 0.f);
    }
    #pragma unroll 4
    for (int kk4 = 0; kk4 < 16; ++kk4) {
      float4 kv0 = *(const float4*)&Ks[tx * 3 + 0][kk4 * 4];
      float4 kv1 = *(const float4*)&Ks[tx * 3 + 1][kk4 * 4];
      float4 kv2 = *(const float4*)&Ks[tx * 3 + 2][kk4 * 4];
      int qc = (kk4 ^ rswz) * 4;
      #pragma unroll
      for (int i = 0; i < 8; ++i) {
        float4 qv = *(const float4*)&Qs[ty * 8 + i][qc];
        acc[i][0] = fmaf(qv.x, kv0.x, acc[i][0]); acc[i][0] = fmaf(qv.y, kv0.y, acc[i][0]);
        acc[i][0] = fmaf(qv.z, kv0.z, acc[i][0]); acc[i][0] = fmaf(qv.w, kv0.w, acc[i][0]);
        acc[i][1] = fmaf(qv.x, kv1.x, acc[i][1]); acc[i][1] = fmaf(qv.y, kv1.y, acc[i][1]);
        acc[i][1] = fmaf(qv.z, kv1.z, acc[i][1]); acc[i][1] = fmaf(qv.w, kv1.w, acc[i][1]);
        acc[i][2] = fmaf(qv.x, kv2.x, acc[i][2]); acc[i][2] = fmaf(qv.y, kv2.y, acc[i][2]);
        acc[i][2] = fmaf(qv.z, kv2.z, acc[i][2]); acc[i][2] = fmaf(qv.w, kv2.w, acc[i][2]);
      }
    }
    __syncthreads();
    if (it < 7) {
      #pragma unroll
      for (int p = 0; p < 8; ++p) {
        int sw = (lr[p] >> 3) & 3;
        *(float4*)&Qs[lr[p]][(lc[p] ^ sw) * 4] = pq[p];
      }
      #pragma unroll
      for (int p = 0; p < 3; ++p) *(float4*)&Ks[kr[p]][kc[p] * 4] = pk[p];
      __syncthreads();
    }
  }

  const bool valid = (tx < 15);
  float c0 = 0.f, c1 = 0.f, c2 = 0.f;
  if (valid) {
    c0 = cvec[b * U_ + tx * 3 + 0];
    c1 = cvec[b * U_ + tx * 3 + 1];
    c2 = cvec[b * U_ + tx * 3 + 2];
  }
  #pragma unroll
  for (int i = 0; i < 8; ++i) {
    float s0 = acc[i][0] + c0, s1 = acc[i][1] + c1, s2 = acc[i][2] + c2;
    float jmax = valid ? fmaxf(fmaxf(s0, s1), s2) : -3.4e38f;
    float jsum = valid ? (s0 + s1 + s2) : 0.f;
    #pragma unroll
    for (int m = 8; m; m >>= 1) {
      jmax = fmaxf(jmax, __shfl_xor(jmax, m, 64));
      jsum += __shfl_xor(jsum, m, 64);
    }
    if (tx == 0) meas[(size_t)b * L_ + l0 + ty * 8 + i] = jmax - jsum * (1.0f / 45.0f);
  }
}

// ==== same GEMM for scores: sc[b][j][l] = (K[l].qw[j] + d[j]) * SCALE ====
__global__ __launch_bounds__(256) void scores2_k(const float* __restrict__ K,
    const float* __restrict__ qw, const float* __restrict__ dvec, float* __restrict__ sc) {
  const int b = blockIdx.y;
  const int l0 = blockIdx.x * 128;
  const int t = threadIdx.x;
  const int tx = t & 15, ty = t >> 4;
  const int rswz = ty & 3;

  __shared__ float Qs[128][68];
  __shared__ float Ks[48][68];

  float acc[8][3];
  #pragma unroll
  for (int i = 0; i < 8; ++i) { acc[i][0] = 0.f; acc[i][1] = 0.f; acc[i][2] = 0.f; }

  const float4* K4  = (const float4*)(K + ((size_t)b * L_ + l0) * 512);
  const float4* qw4 = (const float4*)(qw + (size_t)b * U_ * 512);

  float4 pq[8], pk[3];
  int lr[8], lc[8], kr[3], kc[3];
  #pragma unroll
  for (int p = 0; p < 8; ++p) { int idx = p * 256 + t; lr[p] = idx >> 4; lc[p] = idx & 15; }
  #pragma unroll
  for (int p = 0; p < 3; ++p) { int idx = p * 256 + t; kr[p] = idx >> 4; kc[p] = idx & 15; }

  #pragma unroll
  for (int p = 0; p < 8; ++p) pq[p] = K4[(size_t)lr[p] * 128 + lc[p]];
  #pragma unroll
  for (int p = 0; p < 3; ++p)
    pk[p] = (kr[p] < U_) ? qw4[(size_t)kr[p] * 128 + kc[p]] : make_float4(0.f, 0.f, 0.f, 0.f);

  #pragma unroll
  for (int p = 0; p < 8; ++p) {
    int sw = (lr[p] >> 3) & 3;
    *(float4*)&Qs[lr[p]][(lc[p] ^ sw) * 4] = pq[p];
  }
  #pragma unroll
  for (int p = 0; p < 3; ++p) *(float4*)&Ks[kr[p]][kc[p] * 4] = pk[p];
  __syncthreads();

  for (int it = 0; it < 8; ++it) {
    if (it < 7) {
      int k0 = (it + 1) * 16;
      #pragma unroll
      for (int p = 0; p < 8; ++p) pq[p] = K4[(size_t)lr[p] * 128 + k0 + lc[p]];
      #pragma unroll
      for (int p = 0; p < 3; ++p)
        pk[p] = (kr[p] < U_) ? qw4[(size_t)kr[p] * 128 + k0 + kc[p]] : make_float4(0.f, 0.f, 0.f, 0.f);
    }
    #pragma unroll 4
    for (int kk4 = 0; kk4 < 16; ++kk4) {
      float4 kv0 = *(const float4*)&Ks[tx * 3 + 0][kk4 * 4];
      float4 kv1 = *(const float4*)&Ks[tx * 3 + 1][kk4 * 4];
      float4 kv2 = *(const float4*)&Ks[tx * 3 + 2][kk4 * 4];
      int qc = (kk4 ^ rswz) * 4;
      #pragma unroll
      for (int i = 0; i < 8; ++i) {
        float4 qv = *(const float4*)&Qs[ty * 8 + i][qc];
        acc[i][0] = fmaf(qv.x, kv0.x, acc[i][0]); acc[i][0] = fmaf(qv.y, kv0.y, acc[i][0]);
        acc[i][0] = fmaf(qv.z, kv0.z, acc[i][0]); acc[i][0] = fmaf(qv.w, kv0.w, acc[i][0]);
        acc[i][1] = fmaf(qv.x, kv1.x, acc[i][1]); acc[i][1] = fmaf(qv.y, kv1.y, acc[i][1]);
        acc[i][1] = fmaf(qv.z, kv1.z, acc[i][1]); acc[i][1] = fmaf(qv.w, kv1.w, acc[i][1]);
        acc[i][2] = fmaf(qv.x, kv2.x, acc[i][2]); acc[i][2] = fmaf(qv.y, kv2.y, acc[i][2]);
        acc[i][2] = fmaf(qv.z, kv2.z, acc[i][2]); acc[i][2] = fmaf(qv.w, kv2.w, acc[i][2]);
      }
    }
    __syncthreads();
    if (it < 7) {
      #pragma unroll
      for (int p = 0; p < 8; ++p) {
        int sw = (lr[p] >> 3) & 3;
        *(float4*)&Qs[lr[p]][(lc[p] ^ sw) * 4] = pq[p];
      }
      #pragma unroll
      for (int p = 0; p < 3; ++p) *(float4*)&Ks[kr[p]][kc[p] * 4] = pk[p];
      __syncthreads();
    }
  }

  if (tx < 15) {
    float d0 = dvec[b * U_ + tx * 3 + 0];
    float d1 = dvec[b * U_ + tx * 3 + 1];
    float d2 = dvec[b * U_ + tx * 3 + 2];
    #pragma unroll
    for (int i = 0; i < 8; ++i) {
      int l = l0 + ty * 8 + i;
      sc[((size_t)(b * U_ + tx * 3 + 0)) * 4096 + l] = (acc[i][0] + d0) * SCALE_;
      sc[((size_t)(b * U_ + tx * 3 + 1)) * 4096 + l] = (acc[i][1] + d1) * SCALE_;
      sc[((size_t)(b * U_ + tx * 3 + 2)) * 4096 + l] = (acc[i][2] + d2) * SCALE_;
    }
  }
}

// ---- top-45 indices per batch (iterative argmax; ties -> lower index) ----
__global__ __launch_bounds__(256) void topk_k(const float* __restrict__ meas, int* __restrict__ topI) {
  int b = blockIdx.x, t = threadIdx.x;
  __shared__ unsigned long long keys[4096];
  __shared__ unsigned long long wred[4];
  for (int i = t; i < 4096; i += 256) {
    float m = meas[(size_t)b * 4096 + i];
    unsigned u = __float_as_uint(m);
    u = (u & 0x80000000u) ? ~u : (u | 0x80000000u);
    keys[i] = ((unsigned long long)u << 32) | (unsigned)(4095 - i);
  }
  __syncthreads();
  for (int it = 0; it < U_; ++it) {
    unsigned long long lm = 0ull;
    for (int i = t; i < 4096; i += 256) { unsigned long long k = keys[i]; lm = k > lm ? k : lm; }
    #pragma unroll
    for (int m = 32; m; m >>= 1) { unsigned long long o = __shfl_xor(lm, m, 64); lm = o > lm ? o : lm; }
    if ((t & 63) == 0) wred[t >> 6] = lm;
    __syncthreads();
    if (t == 0) {
      unsigned long long f = wred[0];
      for (int k2 = 1; k2 < 4; ++k2) f = wred[k2] > f ? wred[k2] : f;
      int idxl = 4095 - (int)(f & 0xFFFFFFFFull);
      topI[b * U_ + it] = idxl;
      keys[idxl] = 0ull;
    }
    __syncthreads();
  }
}

// ---- softmax in place over each score row of 4096 ----
__global__ __launch_bounds__(256) void softmax_k(float* __restrict__ sc) {
  int row = blockIdx.x;
  int t = threadIdx.x;
  float* s = sc + (size_t)row * 4096;
  __shared__ float buf[4096];
  __shared__ float red[4];
  float4* b4 = (float4*)buf;
  float4* s4 = (float4*)s;
  float lmax = -3.4e38f;
  for (int i = t; i < 1024; i += 256) {
    float4 v = s4[i]; b4[i] = v;
    lmax = fmaxf(lmax, fmaxf(fmaxf(v.x, v.y), fmaxf(v.z, v.w)));
  }
  lmax = wave_max(lmax);
  if ((t & 63) == 0) red[t >> 6] = lmax;
  __syncthreads();
  float mx = fmaxf(fmaxf(red[0], red[1]), fmaxf(red[2], red[3]));
  __syncthreads();
  float lsum = 0.0f;
  for (int i = t; i < 1024; i += 256) {
    float4 v = b4[i];
    v.x = expf(v.x - mx); v.y = expf(v.y - mx); v.z = expf(v.z - mx); v.w = expf(v.w - mx);
    b4[i] = v;
    lsum += (v.x + v.y) + (v.z + v.w);
  }
  lsum = wave_sum(lsum);
  if ((t & 63) == 0) red[t >> 6] = lsum;
  __syncthreads();
  float inv = 1.0f / (red[0] + red[1] + red[2] + red[3]);
  for (int i = t; i < 1024; i += 256) {
    float4 v = b4[i];
    v.x *= inv; v.y *= inv; v.z *= inv; v.w *= inv;
    s4[i] = v;
  }
}

// ==== attnV as partial GEMM: part[ks][b][i][d] over l in [ks*512, ks*512+512) ====
// grid (b=8, ks=8, dh=4), block 256 = 16 tx (3 i) x 16 ty (8 d); N-chunk = 128 d
__global__ __launch_bounds__(256) void attnv2_k(const float* __restrict__ V,
    const float* __restrict__ attn, float* __restrict__ part) {
  const int b = blockIdx.x, ks = blockIdx.y, dh = blockIdx.z;
  const int l0 = ks * 512, d0 = dh * 128;
  const int t = threadIdx.x;
  const int tx = t & 15, ty = t >> 4;

  __shared__ float attn_s[48][516];    // 45 valid rows, l-chunk of 512
  __shared__ float Vs[2][16][128];     // double-buffered V tile

  const float* attnb = attn + (size_t)b * U_ * 4096;
  for (int idx = t; idx < 48 * 128; idx += 256) {
    int row = idx >> 7, c4 = idx & 127;
    int rr = row < U_ ? row : U_ - 1;   // clamp: rows 45-47 computed but discarded
    *(float4*)&attn_s[row][c4 * 4] = *(const float4*)&attnb[(size_t)rr * 4096 + l0 + c4 * 4];
  }

  const float* Vb = V + ((size_t)b * L_ + l0) * 512 + d0;
  int vrow[2], vc4[2];
  float4 pv[2];
  #pragma unroll
  for (int p = 0; p < 2; ++p) { int idx = p * 256 + t; vrow[p] = idx >> 5; vc4[p] = idx & 31; }
  #pragma unroll
  for (int p = 0; p < 2; ++p) pv[p] = *(const float4*)&Vb[(size_t)vrow[p] * 512 + vc4[p] * 4];
  #pragma unroll
  for (int p = 0; p < 2; ++p) *(float4*)&Vs[0][vrow[p]][vc4[p] * 4] = pv[p];
  __syncthreads();

  float4 acc[3][2];
  #pragma unroll
  for (int r = 0; r < 3; ++r) {
    acc[r][0] = make_float4(0.f, 0.f, 0.f, 0.f);
    acc[r][1] = make_float4(0.f, 0.f, 0.f, 0.f);
  }

  for (int sc2 = 0; sc2 < 32; ++sc2) {
    const int cur = sc2 & 1;
    if (sc2 < 31) {
      #pragma unroll
      for (int p = 0; p < 2; ++p)
        pv[p] = *(const float4*)&Vb[(size_t)((sc2 + 1) * 16 + vrow[p]) * 512 + vc4[p] * 4];
    }
    float4 pa[3][4];
    #pragma unroll
    for (int r = 0; r < 3; ++r)
      #pragma unroll
      for (int q = 0; q < 4; ++q)
        pa[r][q] = *(const float4*)&attn_s[tx * 3 + r][sc2 * 16 + q * 4];
    #pragma unroll
    for (int l = 0; l < 16; ++l) {
      float4 v0 = *(const float4*)&Vs[cur][l][ty * 8];
      float4 v1 = *(const float4*)&Vs[cur][l][ty * 8 + 4];
      #pragma unroll
      for (int r = 0; r < 3; ++r) {
        float a;
        if ((l & 3) == 0) a = pa[r][l >> 2].x;
        else if ((l & 3) == 1) a = pa[r][l >> 2].y;
        else if ((l & 3) == 2) a = pa[r][l >> 2].z;
        else a = pa[r][l >> 2].w;
        acc[r][0].x = fmaf(a, v0.x, acc[r][0].x);
        acc[r][0].y = fmaf(a, v0.y, acc[r][0].y);
        acc[r][0].z = fmaf(a, v0.z, acc[r][0].z);
        acc[r][0].w = fmaf(a, v0.w, acc[r][0].w);
        acc[r][1].x = fmaf(a, v1.x, acc[r][1].x);
        acc[r][1].y = fmaf(a, v1.y, acc[r][1].y);
        acc[r][1].z = fmaf(a, v1.z, acc[r][1].z);
        acc[r][1].w = fmaf(a, v1.w, acc[r][1].w);
      }
    }
    if (sc2 < 31) {
      #pragma unroll
      for (int p = 0; p < 2; ++p) *(float4*)&Vs[cur ^ 1][vrow[p]][vc4[p] * 4] = pv[p];
      __syncthreads();
    }
  }

  #pragma unroll
  for (int r = 0; r < 3; ++r) {
    int i = tx * 3 + r;
    if (i < U_) {
      float* dst = part + (((size_t)(ks * 8 + b)) * U_ + i) * 512 + d0 + ty * 8;
      *(float4*)dst = acc[r][0];
      *(float4*)(dst + 4) = acc[r][1];
    }
  }
}

__global__ __launch_bounds__(256) void attnvred_k(const float* __restrict__ part,
                                                  float* __restrict__ av) {
  int x = blockIdx.x * 256 + threadIdx.x;
  float s = 0.0f;
  #pragma unroll
  for (int ls = 0; ls < 8; ++ls) s += part[(size_t)ls * 184320 + x];
  av[x] = s;
}

// ---- output: base fill (row-mean of Vp) + scatter s1 rows at topI ----
__global__ __launch_bounds__(256) void output_k(const float* __restrict__ V,
    const float* __restrict__ wvmean, const float* __restrict__ bvp,
    const int* __restrict__ topI, const float* __restrict__ s1, float* __restrict__ outp) {
  int b = blockIdx.y, tile = blockIdx.x;
  int l0 = tile * 64;
  int t = threadIdx.x, w = t >> 6, lane = t & 63;
  __shared__ int sel[64];
  if (t < 64) sel[t] = -1;
  __syncthreads();
  if (t < U_) {
    int lj = topI[b * U_ + t] - l0;
    if (lj >= 0 && lj < 64) sel[lj] = t;
  }
  __syncthreads();
  const float4* wv4 = (const float4*)wvmean;
  float4 wa = wv4[lane], wb = wv4[64 + lane];
  float bv = bvp[0];
  const float4* V4 = (const float4*)(V + (size_t)b * L_ * 512);
  float4* out4 = (float4*)(outp + (size_t)b * L_ * 512);
  const float4* s14 = (const float4*)s1;
  for (int r = w; r < 64; r += 4) {
    int l = l0 + r;
    int j = sel[r];
    float4 o1, o2;
    if (j >= 0) {
      o1 = s14[((size_t)(b * U_ + j)) * 128 + lane];
      o2 = s14[((size_t)(b * U_ + j)) * 128 + 64 + lane];
    } else {
      float4 va = V4[(size_t)l * 128 + lane];
      float4 vb = V4[(size_t)l * 128 + 64 + lane];
      float s = va.x * wa.x + va.y * wa.y + va.z * wa.z + va.w * wa.w
              + vb.x * wb.x + vb.y * wb.y + vb.z * wb.z + vb.w * wb.w;
      s = wave_sum(s);
      float base = s + bv;
      o1 = make_float4(base, base, base, base);
      o2 = o1;
    }
    out4[(size_t)l * 128 + lane] = o1;
    out4[(size_t)l * 128 + 64 + lane] = o2;
  }
}

extern "C" void kernel_launch(void* const* d_in, const int* in_sizes, int n_in,
                              void* d_out, int out_size, void* d_ws, size_t ws_size,
                              hipStream_t stream) {
  (void)in_sizes; (void)n_in; (void)out_size; (void)ws_size;
  const float* Q  = (const float*)d_in[0];
  const float* K  = (const float*)d_in[1];
  const float* V  = (const float*)d_in[2];
  const float* WQ = (const float*)d_in[3];
  const float* bQ = (const float*)d_in[4];
  const float* WK = (const float*)d_in[5];
  const float* bK = (const float*)d_in[6];
  const float* WV = (const float*)d_in[7];
  const float* bV = (const float*)d_in[8];
  const int* kidx = (const int*)d_in[9];
  float* ws = (float*)d_ws;
  float* out = (float*)d_out;

  float* wvmean = ws + OFF_WVMEAN;
  float* bvm    = ws + OFF_BV;
  float* wqt    = ws + OFF_WQT;
  float* wkt    = ws + OFF_WKT;
  float* kbar   = ws + OFF_KBAR;
  float* kw     = ws + OFF_KW;
  float* cvec   = ws + OFF_CVEC;
  float* measp  = ws + OFF_MEAS;
  int*   topI   = (int*)(ws + OFF_TOPI);
  float* qbar   = ws + OFF_QBAR;
  float* qw     = ws + OFF_QW;
  float* dvec   = ws + OFF_DVEC;
  float* sc     = ws + OFF_SC;
  float* partp  = ws + OFF_PART;
  float* attnv  = ws + OFF_ATTNV;
  float* s1     = ws + OFF_S1;

  transpose_k<<<dim3(16, 16, 2), dim3(32, 8), 0, stream>>>(WQ, WK, wqt, wkt);
  wvmean_k<<<dim3(8), dim3(256), 0, stream>>>(WV, bV, wvmean, bvm);

  rows_matmul_k<<<dim3(72), dim3(512), 0, stream>>>(K, kidx, WK, bK, bQ, cvec, kbar);
  rows_matmul_k<<<dim3(72), dim3(512), 0, stream>>>(kbar, nullptr, wqt, nullptr, nullptr, nullptr, kw);
  meas2_k<<<dim3(32, 8), dim3(256), 0, stream>>>(Q, kw, cvec, measp);
  topk_k<<<dim3(8), dim3(256), 0, stream>>>(measp, topI);
  rows_matmul_k<<<dim3(72), dim3(512), 0, stream>>>(Q, topI, WQ, bQ, bK, dvec, qbar);
  rows_matmul_k<<<dim3(72), dim3(512), 0, stream>>>(qbar, nullptr, wkt, nullptr, nullptr, nullptr, qw);
  scores2_k<<<dim3(32, 8), dim3(256), 0, stream>>>(K, qw, dvec, sc);
  softmax_k<<<dim3(360), dim3(256), 0, stream>>>(sc);
  attnv2_k<<<dim3(8, 8, 4), dim3(256), 0, stream>>>(V, sc, partp);
  attnvred_k<<<dim3(720), dim3(256), 0, stream>>>(partp, attnv);
  rows_matmul_k<<<dim3(72), dim3(512), 0, stream>>>(attnv, nullptr, WV, bV, nullptr, nullptr, s1);
  output_k<<<dim3(64, 8), dim3(256), 0, stream>>>(V, wvmean, bvm, topI, s1, out);
}

// Round 4
// 482.907 us; speedup vs baseline: 1.4827x; 1.0630x over previous
//
#include <hip/hip_runtime.h>
#include <math.h>

static constexpr int B_ = 8;
static constexpr int L_ = 4096;
static constexpr int D_ = 512;
static constexpr int U_ = 45;
static constexpr float SCALE_ = 0.04419417382415922f; // 1/sqrt(512)

// ---- workspace layout (offsets in floats) ----
static constexpr size_t OFF_WVMEAN = 0;                      // 512
static constexpr size_t OFF_BV     = 512;                    // 64
static constexpr size_t OFF_WQT    = 576;                    // 512*512
static constexpr size_t OFF_WKT    = OFF_WQT + 262144;       // 512*512
static constexpr size_t OFF_KBAR   = OFF_WKT + 262144;       // 8*45*512
static constexpr size_t OFF_KW     = OFF_KBAR + 184320;      // 8*45*512
static constexpr size_t OFF_CVEC   = OFF_KW + 184320;        // 384
static constexpr size_t OFF_MEAS   = OFF_CVEC + 384;         // 8*4096
static constexpr size_t OFF_TOPI   = OFF_MEAS + 32768;       // 384 (ints)
static constexpr size_t OFF_QBAR   = OFF_TOPI + 384;         // 8*45*512
static constexpr size_t OFF_QW     = OFF_QBAR + 184320;      // 8*45*512
static constexpr size_t OFF_DVEC   = OFF_QW + 184320;        // 384
static constexpr size_t OFF_SC     = OFF_DVEC + 384;         // 8*45*4096
static constexpr size_t OFF_PART   = OFF_SC + 1474560;       // 8 slabs * 8*45*512
static constexpr size_t OFF_ATTNV  = OFF_PART + 1474560;     // 8*45*512
static constexpr size_t OFF_S1     = OFF_ATTNV + 184320;     // 8*45*512

__device__ __forceinline__ float wave_sum(float v) {
  #pragma unroll
  for (int m = 32; m; m >>= 1) v += __shfl_xor(v, m, 64);
  return v;
}
__device__ __forceinline__ float wave_max(float v) {
  #pragma unroll
  for (int m = 32; m; m >>= 1) v = fmaxf(v, __shfl_xor(v, m, 64));
  return v;
}

// ---- transpose WQ, WK (512x512) into ws so later GEMM-ish kernels read coalesced ----
__global__ __launch_bounds__(256) void transpose_k(const float* __restrict__ WQ,
    const float* __restrict__ WK, float* __restrict__ wqt, float* __restrict__ wkt) {
  const float* src = blockIdx.z ? WK : WQ;
  float* dst = blockIdx.z ? wkt : wqt;
  __shared__ float tile[32][33];
  int tx = threadIdx.x, ty = threadIdx.y;
  int x = blockIdx.x * 32 + tx;
  int y0 = blockIdx.y * 32;
  for (int r = ty; r < 32; r += 8) tile[r][tx] = src[(size_t)(y0 + r) * 512 + x];
  __syncthreads();
  int xo = y0 + tx;
  int yo0 = blockIdx.x * 32;
  for (int r = ty; r < 32; r += 8) dst[(size_t)(yo0 + r) * 512 + xo] = tile[tx][r];
}

// ---- wv_mean[m] = mean_d WV[m][d]; bv_mean = mean(bV) ----
__global__ __launch_bounds__(256) void wvmean_k(const float* __restrict__ WV,
    const float* __restrict__ bV, float* __restrict__ wvmean, float* __restrict__ bvout) {
  int t = threadIdx.x, w = t >> 6, lane = t & 63;
  const float4* W4 = (const float4*)WV;
  int mbase = (blockIdx.x * 4 + w) * 16;
  for (int i = 0; i < 16; ++i) {
    int m = mbase + i;
    float4 a = W4[(size_t)m * 128 + lane];
    float4 c = W4[(size_t)m * 128 + 64 + lane];
    float s = ((a.x + a.y) + (a.z + a.w)) + ((c.x + c.y) + (c.z + c.w));
    s = wave_sum(s);
    if (lane == 0) wvmean[m] = s * (1.0f / 512.0f);
  }
  if (blockIdx.x == 0 && w == 0) {
    const float4* b4 = (const float4*)bV;
    float4 a = b4[lane], c = b4[64 + lane];
    float s = ((a.x + a.y) + (a.z + a.w)) + ((c.x + c.y) + (c.z + c.w));
    s = wave_sum(s);
    if (lane == 0) bvout[0] = s * (1.0f / 512.0f);
  }
}

// ---- generic: out[b][j][:] = row(b,j) @ W + bias ; optional aux[b][j] = out_row . avec ----
__global__ __launch_bounds__(512) void rows_matmul_k(const float* __restrict__ src,
    const int* __restrict__ idx, const float* __restrict__ W, const float* __restrict__ bias,
    const float* __restrict__ avec, float* __restrict__ aux, float* __restrict__ out) {
  int blk = blockIdx.x;
  int b = blk / 9, g = blk % 9;
  int j0 = g * 5;
  int t = threadIdx.x;
  __shared__ float rows[5][512];
  for (int r = 0; r < 5; ++r) {
    int j = j0 + r;
    const float* s = idx ? (src + ((size_t)b * L_ + idx[b * U_ + j]) * 512)
                         : (src + ((size_t)(b * U_ + j)) * 512);
    rows[r][t] = s[t];
  }
  __syncthreads();
  float bi = bias ? bias[t] : 0.0f;
  float a0 = bi, a1 = bi, a2 = bi, a3 = bi, a4 = bi;
  #pragma unroll 4
  for (int m = 0; m < 512; ++m) {
    float wv = W[(size_t)m * 512 + t];
    a0 = fmaf(rows[0][m], wv, a0);
    a1 = fmaf(rows[1][m], wv, a1);
    a2 = fmaf(rows[2][m], wv, a2);
    a3 = fmaf(rows[3][m], wv, a3);
    a4 = fmaf(rows[4][m], wv, a4);
  }
  out[((size_t)(b * U_ + j0 + 0)) * 512 + t] = a0;
  out[((size_t)(b * U_ + j0 + 1)) * 512 + t] = a1;
  out[((size_t)(b * U_ + j0 + 2)) * 512 + t] = a2;
  out[((size_t)(b * U_ + j0 + 3)) * 512 + t] = a3;
  out[((size_t)(b * U_ + j0 + 4)) * 512 + t] = a4;
  if (avec) {
    float av = avec[t];
    __shared__ float red[8];
    float accs[5] = {a0, a1, a2, a3, a4};
    #pragma unroll
    for (int r = 0; r < 5; ++r) {
      float v = wave_sum(accs[r] * av);
      if ((t & 63) == 0) red[t >> 6] = v;
      __syncthreads();
      if (t == 0) {
        float s2 = 0.0f;
        #pragma unroll
        for (int k2 = 0; k2 < 8; ++k2) s2 += red[k2];
        aux[b * U_ + j0 + r] = s2;
      }
      __syncthreads();
    }
  }
}

// ==== register-blocked GEMM for meas: S = Q_tile[64x512] @ kw^T[512x48] ====
// grid (64, 8), block 256 = 16 tx (3 j) x 16 ty (4 l) -> 2 blocks/CU, 2 waves/SIMD
__global__ __launch_bounds__(256) void meas2_k(const float* __restrict__ Q,
    const float* __restrict__ kw, const float* __restrict__ cvec, float* __restrict__ meas) {
  const int b = blockIdx.y;
  const int l0 = blockIdx.x * 64;
  const int t = threadIdx.x;
  const int tx = t & 15, ty = t >> 4;
  const int rswz = (ty >> 1) & 3;   // matches store swizzle (row>>3)&3 for rows ty*4+i

  __shared__ float Qs[64][68];
  __shared__ float Ks[48][68];

  float acc[4][3];
  #pragma unroll
  for (int i = 0; i < 4; ++i) { acc[i][0] = 0.f; acc[i][1] = 0.f; acc[i][2] = 0.f; }

  const float4* Q4  = (const float4*)(Q + ((size_t)b * L_ + l0) * 512);
  const float4* kw4 = (const float4*)(kw + (size_t)b * U_ * 512);

  float4 pq[4], pk[3];
  int lr[4], lc[4], kr[3], kc[3];
  #pragma unroll
  for (int p = 0; p < 4; ++p) { int idx = p * 256 + t; lr[p] = idx >> 4; lc[p] = idx & 15; }
  #pragma unroll
  for (int p = 0; p < 3; ++p) { int idx = p * 256 + t; kr[p] = idx >> 4; kc[p] = idx & 15; }

  #pragma unroll
  for (int p = 0; p < 4; ++p) pq[p] = Q4[(size_t)lr[p] * 128 + lc[p]];
  #pragma unroll
  for (int p = 0; p < 3; ++p)
    pk[p] = (kr[p] < U_) ? kw4[(size_t)kr[p] * 128 + kc[p]] : make_float4(0.f, 0.f, 0.f, 0.f);

  #pragma unroll
  for (int p = 0; p < 4; ++p) {
    int sw = (lr[p] >> 3) & 3;
    *(float4*)&Qs[lr[p]][(lc[p] ^ sw) * 4] = pq[p];
  }
  #pragma unroll
  for (int p = 0; p < 3; ++p) *(float4*)&Ks[kr[p]][kc[p] * 4] = pk[p];
  __syncthreads();

  for (int it = 0; it < 8; ++it) {
    if (it < 7) {
      int k0 = (it + 1) * 16;
      #pragma unroll
      for (int p = 0; p < 4; ++p) pq[p] = Q4[(size_t)lr[p] * 128 + k0 + lc[p]];
      #pragma unroll
      for (int p = 0; p < 3; ++p)
        pk[p] = (kr[p] < U_) ? kw4[(size_t)kr[p] * 128 + k0 + kc[p]] : make_float4(0.f, 0.f, 0.f, 0.f);
    }
    #pragma unroll 4
    for (int kk4 = 0; kk4 < 16; ++kk4) {
      float4 kv0 = *(const float4*)&Ks[tx * 3 + 0][kk4 * 4];
      float4 kv1 = *(const float4*)&Ks[tx * 3 + 1][kk4 * 4];
      float4 kv2 = *(const float4*)&Ks[tx * 3 + 2][kk4 * 4];
      int qc = (kk4 ^ rswz) * 4;
      #pragma unroll
      for (int i = 0; i < 4; ++i) {
        float4 qv = *(const float4*)&Qs[ty * 4 + i][qc];
        acc[i][0] = fmaf(qv.x, kv0.x, acc[i][0]); acc[i][0] = fmaf(qv.y, kv0.y, acc[i][0]);
        acc[i][0] = fmaf(qv.z, kv0.z, acc[i][0]); acc[i][0] = fmaf(qv.w, kv0.w, acc[i][0]);
        acc[i][1] = fmaf(qv.x, kv1.x, acc[i][1]); acc[i][1] = fmaf(qv.y, kv1.y, acc[i][1]);
        acc[i][1] = fmaf(qv.z, kv1.z, acc[i][1]); acc[i][1] = fmaf(qv.w, kv1.w, acc[i][1]);
        acc[i][2] = fmaf(qv.x, kv2.x, acc[i][2]); acc[i][2] = fmaf(qv.y, kv2.y, acc[i][2]);
        acc[i][2] = fmaf(qv.z, kv2.z, acc[i][2]); acc[i][2] = fmaf(qv.w, kv2.w, acc[i][2]);
      }
    }
    __syncthreads();
    if (it < 7) {
      #pragma unroll
      for (int p = 0; p < 4; ++p) {
        int sw = (lr[p] >> 3) & 3;
        *(float4*)&Qs[lr[p]][(lc[p] ^ sw) * 4] = pq[p];
      }
      #pragma unroll
      for (int p = 0; p < 3; ++p) *(float4*)&Ks[kr[p]][kc[p] * 4] = pk[p];
      __syncthreads();
    }
  }

  const bool valid = (tx < 15);
  float c0 = 0.f, c1 = 0.f, c2 = 0.f;
  if (valid) {
    c0 = cvec[b * U_ + tx * 3 + 0];
    c1 = cvec[b * U_ + tx * 3 + 1];
    c2 = cvec[b * U_ + tx * 3 + 2];
  }
  #pragma unroll
  for (int i = 0; i < 4; ++i) {
    float s0 = acc[i][0] + c0, s1 = acc[i][1] + c1, s2 = acc[i][2] + c2;
    float jmax = valid ? fmaxf(fmaxf(s0, s1), s2) : -3.4e38f;
    float jsum = valid ? (s0 + s1 + s2) : 0.f;
    #pragma unroll
    for (int m = 8; m; m >>= 1) {
      jmax = fmaxf(jmax, __shfl_xor(jmax, m, 64));
      jsum += __shfl_xor(jsum, m, 64);
    }
    if (tx == 0) meas[(size_t)b * L_ + l0 + ty * 4 + i] = jmax - jsum * (1.0f / 45.0f);
  }
}

// ==== same GEMM for scores: sc[b][j][l] = (K[l].qw[j] + d[j]) * SCALE ====
__global__ __launch_bounds__(256) void scores2_k(const float* __restrict__ K,
    const float* __restrict__ qw, const float* __restrict__ dvec, float* __restrict__ sc) {
  const int b = blockIdx.y;
  const int l0 = blockIdx.x * 64;
  const int t = threadIdx.x;
  const int tx = t & 15, ty = t >> 4;
  const int rswz = (ty >> 1) & 3;

  __shared__ float Qs[64][68];   // K-tile
  __shared__ float Ks[48][68];   // qw rows

  float acc[4][3];
  #pragma unroll
  for (int i = 0; i < 4; ++i) { acc[i][0] = 0.f; acc[i][1] = 0.f; acc[i][2] = 0.f; }

  const float4* K4  = (const float4*)(K + ((size_t)b * L_ + l0) * 512);
  const float4* qw4 = (const float4*)(qw + (size_t)b * U_ * 512);

  float4 pq[4], pk[3];
  int lr[4], lc[4], kr[3], kc[3];
  #pragma unroll
  for (int p = 0; p < 4; ++p) { int idx = p * 256 + t; lr[p] = idx >> 4; lc[p] = idx & 15; }
  #pragma unroll
  for (int p = 0; p < 3; ++p) { int idx = p * 256 + t; kr[p] = idx >> 4; kc[p] = idx & 15; }

  #pragma unroll
  for (int p = 0; p < 4; ++p) pq[p] = K4[(size_t)lr[p] * 128 + lc[p]];
  #pragma unroll
  for (int p = 0; p < 3; ++p)
    pk[p] = (kr[p] < U_) ? qw4[(size_t)kr[p] * 128 + kc[p]] : make_float4(0.f, 0.f, 0.f, 0.f);

  #pragma unroll
  for (int p = 0; p < 4; ++p) {
    int sw = (lr[p] >> 3) & 3;
    *(float4*)&Qs[lr[p]][(lc[p] ^ sw) * 4] = pq[p];
  }
  #pragma unroll
  for (int p = 0; p < 3; ++p) *(float4*)&Ks[kr[p]][kc[p] * 4] = pk[p];
  __syncthreads();

  for (int it = 0; it < 8; ++it) {
    if (it < 7) {
      int k0 = (it + 1) * 16;
      #pragma unroll
      for (int p = 0; p < 4; ++p) pq[p] = K4[(size_t)lr[p] * 128 + k0 + lc[p]];
      #pragma unroll
      for (int p = 0; p < 3; ++p)
        pk[p] = (kr[p] < U_) ? qw4[(size_t)kr[p] * 128 + k0 + kc[p]] : make_float4(0.f, 0.f, 0.f, 0.f);
    }
    #pragma unroll 4
    for (int kk4 = 0; kk4 < 16; ++kk4) {
      float4 kv0 = *(const float4*)&Ks[tx * 3 + 0][kk4 * 4];
      float4 kv1 = *(const float4*)&Ks[tx * 3 + 1][kk4 * 4];
      float4 kv2 = *(const float4*)&Ks[tx * 3 + 2][kk4 * 4];
      int qc = (kk4 ^ rswz) * 4;
      #pragma unroll
      for (int i = 0; i < 4; ++i) {
        float4 qv = *(const float4*)&Qs[ty * 4 + i][qc];
        acc[i][0] = fmaf(qv.x, kv0.x, acc[i][0]); acc[i][0] = fmaf(qv.y, kv0.y, acc[i][0]);
        acc[i][0] = fmaf(qv.z, kv0.z, acc[i][0]); acc[i][0] = fmaf(qv.w, kv0.w, acc[i][0]);
        acc[i][1] = fmaf(qv.x, kv1.x, acc[i][1]); acc[i][1] = fmaf(qv.y, kv1.y, acc[i][1]);
        acc[i][1] = fmaf(qv.z, kv1.z, acc[i][1]); acc[i][1] = fmaf(qv.w, kv1.w, acc[i][1]);
        acc[i][2] = fmaf(qv.x, kv2.x, acc[i][2]); acc[i][2] = fmaf(qv.y, kv2.y, acc[i][2]);
        acc[i][2] = fmaf(qv.z, kv2.z, acc[i][2]); acc[i][2] = fmaf(qv.w, kv2.w, acc[i][2]);
      }
    }
    __syncthreads();
    if (it < 7) {
      #pragma unroll
      for (int p = 0; p < 4; ++p) {
        int sw = (lr[p] >> 3) & 3;
        *(float4*)&Qs[lr[p]][(lc[p] ^ sw) * 4] = pq[p];
      }
      #pragma unroll
      for (int p = 0; p < 3; ++p) *(float4*)&Ks[kr[p]][kc[p] * 4] = pk[p];
      __syncthreads();
    }
  }

  if (tx < 15) {
    float d0 = dvec[b * U_ + tx * 3 + 0];
    float d1 = dvec[b * U_ + tx * 3 + 1];
    float d2 = dvec[b * U_ + tx * 3 + 2];
    #pragma unroll
    for (int i = 0; i < 4; ++i) {
      int l = l0 + ty * 4 + i;
      sc[((size_t)(b * U_ + tx * 3 + 0)) * 4096 + l] = (acc[i][0] + d0) * SCALE_;
      sc[((size_t)(b * U_ + tx * 3 + 1)) * 4096 + l] = (acc[i][1] + d1) * SCALE_;
      sc[((size_t)(b * U_ + tx * 3 + 2)) * 4096 + l] = (acc[i][2] + d2) * SCALE_;
    }
  }
}

// ---- top-45 indices per batch (iterative argmax; ties -> lower index) ----
__global__ __launch_bounds__(256) void topk_k(const float* __restrict__ meas, int* __restrict__ topI) {
  int b = blockIdx.x, t = threadIdx.x;
  __shared__ unsigned long long keys[4096];
  __shared__ unsigned long long wred[4];
  for (int i = t; i < 4096; i += 256) {
    float m = meas[(size_t)b * 4096 + i];
    unsigned u = __float_as_uint(m);
    u = (u & 0x80000000u) ? ~u : (u | 0x80000000u);
    keys[i] = ((unsigned long long)u << 32) | (unsigned)(4095 - i);
  }
  __syncthreads();
  for (int it = 0; it < U_; ++it) {
    unsigned long long lm = 0ull;
    for (int i = t; i < 4096; i += 256) { unsigned long long k = keys[i]; lm = k > lm ? k : lm; }
    #pragma unroll
    for (int m = 32; m; m >>= 1) { unsigned long long o = __shfl_xor(lm, m, 64); lm = o > lm ? o : lm; }
    if ((t & 63) == 0) wred[t >> 6] = lm;
    __syncthreads();
    if (t == 0) {
      unsigned long long f = wred[0];
      for (int k2 = 1; k2 < 4; ++k2) f = wred[k2] > f ? wred[k2] : f;
      int idxl = 4095 - (int)(f & 0xFFFFFFFFull);
      topI[b * U_ + it] = idxl;
      keys[idxl] = 0ull;
    }
    __syncthreads();
  }
}

// ---- softmax in place over each score row of 4096 ----
__global__ __launch_bounds__(256) void softmax_k(float* __restrict__ sc) {
  int row = blockIdx.x;
  int t = threadIdx.x;
  float* s = sc + (size_t)row * 4096;
  __shared__ float buf[4096];
  __shared__ float red[4];
  float4* b4 = (float4*)buf;
  float4* s4 = (float4*)s;
  float lmax = -3.4e38f;
  for (int i = t; i < 1024; i += 256) {
    float4 v = s4[i]; b4[i] = v;
    lmax = fmaxf(lmax, fmaxf(fmaxf(v.x, v.y), fmaxf(v.z, v.w)));
  }
  lmax = wave_max(lmax);
  if ((t & 63) == 0) red[t >> 6] = lmax;
  __syncthreads();
  float mx = fmaxf(fmaxf(red[0], red[1]), fmaxf(red[2], red[3]));
  __syncthreads();
  float lsum = 0.0f;
  for (int i = t; i < 1024; i += 256) {
    float4 v = b4[i];
    v.x = expf(v.x - mx); v.y = expf(v.y - mx); v.z = expf(v.z - mx); v.w = expf(v.w - mx);
    b4[i] = v;
    lsum += (v.x + v.y) + (v.z + v.w);
  }
  lsum = wave_sum(lsum);
  if ((t & 63) == 0) red[t >> 6] = lsum;
  __syncthreads();
  float inv = 1.0f / (red[0] + red[1] + red[2] + red[3]);
  for (int i = t; i < 1024; i += 256) {
    float4 v = b4[i];
    v.x *= inv; v.y *= inv; v.z *= inv; v.w *= inv;
    s4[i] = v;
  }
}

// ==== attnV as partial GEMM: part[ks][b][i][d] over l in [ks*512, ks*512+512) ====
__global__ __launch_bounds__(256) void attnv2_k(const float* __restrict__ V,
    const float* __restrict__ attn, float* __restrict__ part) {
  const int b = blockIdx.x, ks = blockIdx.y, dh = blockIdx.z;
  const int l0 = ks * 512, d0 = dh * 128;
  const int t = threadIdx.x;
  const int tx = t & 15, ty = t >> 4;

  __shared__ float attn_s[48][516];
  __shared__ float Vs[2][16][128];

  const float* attnb = attn + (size_t)b * U_ * 4096;
  for (int idx = t; idx < 48 * 128; idx += 256) {
    int row = idx >> 7, c4 = idx & 127;
    int rr = row < U_ ? row : U_ - 1;
    *(float4*)&attn_s[row][c4 * 4] = *(const float4*)&attnb[(size_t)rr * 4096 + l0 + c4 * 4];
  }

  const float* Vb = V + ((size_t)b * L_ + l0) * 512 + d0;
  int vrow[2], vc4[2];
  float4 pv[2];
  #pragma unroll
  for (int p = 0; p < 2; ++p) { int idx = p * 256 + t; vrow[p] = idx >> 5; vc4[p] = idx & 31; }
  #pragma unroll
  for (int p = 0; p < 2; ++p) pv[p] = *(const float4*)&Vb[(size_t)vrow[p] * 512 + vc4[p] * 4];
  #pragma unroll
  for (int p = 0; p < 2; ++p) *(float4*)&Vs[0][vrow[p]][vc4[p] * 4] = pv[p];
  __syncthreads();

  float4 acc[3][2];
  #pragma unroll
  for (int r = 0; r < 3; ++r) {
    acc[r][0] = make_float4(0.f, 0.f, 0.f, 0.f);
    acc[r][1] = make_float4(0.f, 0.f, 0.f, 0.f);
  }

  for (int sc2 = 0; sc2 < 32; ++sc2) {
    const int cur = sc2 & 1;
    if (sc2 < 31) {
      #pragma unroll
      for (int p = 0; p < 2; ++p)
        pv[p] = *(const float4*)&Vb[(size_t)((sc2 + 1) * 16 + vrow[p]) * 512 + vc4[p] * 4];
    }
    float4 pa[3][4];
    #pragma unroll
    for (int r = 0; r < 3; ++r)
      #pragma unroll
      for (int q = 0; q < 4; ++q)
        pa[r][q] = *(const float4*)&attn_s[tx * 3 + r][sc2 * 16 + q * 4];
    #pragma unroll
    for (int l = 0; l < 16; ++l) {
      float4 v0 = *(const float4*)&Vs[cur][l][ty * 8];
      float4 v1 = *(const float4*)&Vs[cur][l][ty * 8 + 4];
      #pragma unroll
      for (int r = 0; r < 3; ++r) {
        float a;
        if ((l & 3) == 0) a = pa[r][l >> 2].x;
        else if ((l & 3) == 1) a = pa[r][l >> 2].y;
        else if ((l & 3) == 2) a = pa[r][l >> 2].z;
        else a = pa[r][l >> 2].w;
        acc[r][0].x = fmaf(a, v0.x, acc[r][0].x);
        acc[r][0].y = fmaf(a, v0.y, acc[r][0].y);
        acc[r][0].z = fmaf(a, v0.z, acc[r][0].z);
        acc[r][0].w = fmaf(a, v0.w, acc[r][0].w);
        acc[r][1].x = fmaf(a, v1.x, acc[r][1].x);
        acc[r][1].y = fmaf(a, v1.y, acc[r][1].y);
        acc[r][1].z = fmaf(a, v1.z, acc[r][1].z);
        acc[r][1].w = fmaf(a, v1.w, acc[r][1].w);
      }
    }
    if (sc2 < 31) {
      #pragma unroll
      for (int p = 0; p < 2; ++p) *(float4*)&Vs[cur ^ 1][vrow[p]][vc4[p] * 4] = pv[p];
      __syncthreads();
    }
  }

  #pragma unroll
  for (int r = 0; r < 3; ++r) {
    int i = tx * 3 + r;
    if (i < U_) {
      float* dst = part + (((size_t)(ks * 8 + b)) * U_ + i) * 512 + d0 + ty * 8;
      *(float4*)dst = acc[r][0];
      *(float4*)(dst + 4) = acc[r][1];
    }
  }
}

__global__ __launch_bounds__(256) void attnvred_k(const float* __restrict__ part,
                                                  float* __restrict__ av) {
  int x = blockIdx.x * 256 + threadIdx.x;
  float s = 0.0f;
  #pragma unroll
  for (int ls = 0; ls < 8; ++ls) s += part[(size_t)ls * 184320 + x];
  av[x] = s;
}

// ---- output: base fill (row-mean of Vp) + scatter s1 rows at topI ----
__global__ __launch_bounds__(256) void output_k(const float* __restrict__ V,
    const float* __restrict__ wvmean, const float* __restrict__ bvp,
    const int* __restrict__ topI, const float* __restrict__ s1, float* __restrict__ outp) {
  int b = blockIdx.y, tile = blockIdx.x;
  int l0 = tile * 64;
  int t = threadIdx.x, w = t >> 6, lane = t & 63;
  __shared__ int sel[64];
  if (t < 64) sel[t] = -1;
  __syncthreads();
  if (t < U_) {
    int lj = topI[b * U_ + t] - l0;
    if (lj >= 0 && lj < 64) sel[lj] = t;
  }
  __syncthreads();
  const float4* wv4 = (const float4*)wvmean;
  float4 wa = wv4[lane], wb = wv4[64 + lane];
  float bv = bvp[0];
  const float4* V4 = (const float4*)(V + (size_t)b * L_ * 512);
  float4* out4 = (float4*)(outp + (size_t)b * L_ * 512);
  const float4* s14 = (const float4*)s1;
  for (int r = w; r < 64; r += 4) {
    int l = l0 + r;
    int j = sel[r];
    float4 o1, o2;
    if (j >= 0) {
      o1 = s14[((size_t)(b * U_ + j)) * 128 + lane];
      o2 = s14[((size_t)(b * U_ + j)) * 128 + 64 + lane];
    } else {
      float4 va = V4[(size_t)l * 128 + lane];
      float4 vb = V4[(size_t)l * 128 + 64 + lane];
      float s = va.x * wa.x + va.y * wa.y + va.z * wa.z + va.w * wa.w
              + vb.x * wb.x + vb.y * wb.y + vb.z * wb.z + vb.w * wb.w;
      s = wave_sum(s);
      float base = s + bv;
      o1 = make_float4(base, base, base, base);
      o2 = o1;
    }
    out4[(size_t)l * 128 + lane] = o1;
    out4[(size_t)l * 128 + 64 + lane] = o2;
  }
}

extern "C" void kernel_launch(void* const* d_in, const int* in_sizes, int n_in,
                              void* d_out, int out_size, void* d_ws, size_t ws_size,
                              hipStream_t stream) {
  (void)in_sizes; (void)n_in; (void)out_size; (void)ws_size;
  const float* Q  = (const float*)d_in[0];
  const float* K  = (const float*)d_in[1];
  const float* V  = (const float*)d_in[2];
  const float* WQ = (const float*)d_in[3];
  const float* bQ = (const float*)d_in[4];
  const float* WK = (const float*)d_in[5];
  const float* bK = (const float*)d_in[6];
  const float* WV = (const float*)d_in[7];
  const float* bV = (const float*)d_in[8];
  const int* kidx = (const int*)d_in[9];
  float* ws = (float*)d_ws;
  float* out = (float*)d_out;

  float* wvmean = ws + OFF_WVMEAN;
  float* bvm    = ws + OFF_BV;
  float* wqt    = ws + OFF_WQT;
  float* wkt    = ws + OFF_WKT;
  float* kbar   = ws + OFF_KBAR;
  float* kw     = ws + OFF_KW;
  float* cvec   = ws + OFF_CVEC;
  float* measp  = ws + OFF_MEAS;
  int*   topI   = (int*)(ws + OFF_TOPI);
  float* qbar   = ws + OFF_QBAR;
  float* qw     = ws + OFF_QW;
  float* dvec   = ws + OFF_DVEC;
  float* sc     = ws + OFF_SC;
  float* partp  = ws + OFF_PART;
  float* attnv  = ws + OFF_ATTNV;
  float* s1     = ws + OFF_S1;

  transpose_k<<<dim3(16, 16, 2), dim3(32, 8), 0, stream>>>(WQ, WK, wqt, wkt);
  wvmean_k<<<dim3(8), dim3(256), 0, stream>>>(WV, bV, wvmean, bvm);

  rows_matmul_k<<<dim3(72), dim3(512), 0, stream>>>(K, kidx, WK, bK, bQ, cvec, kbar);
  rows_matmul_k<<<dim3(72), dim3(512), 0, stream>>>(kbar, nullptr, wqt, nullptr, nullptr, nullptr, kw);
  meas2_k<<<dim3(64, 8), dim3(256), 0, stream>>>(Q, kw, cvec, measp);
  topk_k<<<dim3(8), dim3(256), 0, stream>>>(measp, topI);
  rows_matmul_k<<<dim3(72), dim3(512), 0, stream>>>(Q, topI, WQ, bQ, bK, dvec, qbar);
  rows_matmul_k<<<dim3(72), dim3(512), 0, stream>>>(qbar, nullptr, wkt, nullptr, nullptr, nullptr, qw);
  scores2_k<<<dim3(64, 8), dim3(256), 0, stream>>>(K, qw, dvec, sc);
  softmax_k<<<dim3(360), dim3(256), 0, stream>>>(sc);
  attnv2_k<<<dim3(8, 8, 4), dim3(256), 0, stream>>>(V, sc, partp);
  attnvred_k<<<dim3(720), dim3(256), 0, stream>>>(partp, attnv);
  rows_matmul_k<<<dim3(72), dim3(512), 0, stream>>>(attnv, nullptr, WV, bV, nullptr, nullptr, s1);
  output_k<<<dim3(64, 8), dim3(256), 0, stream>>>(V, wvmean, bvm, topI, s1, out);
}